// Round 10
// baseline (76.719 us; speedup 1.0000x reference)
//
#include <hip/hip_runtime.h>
#include <hip/hip_bf16.h>

#define H 16
#define L 4096
#define D 64
#define R 128
#define C2 64
#define NC2 64
#define HN2 (H * NC2)      // 1024 chunks
#define EPS 1e-10f
#define XS_SCALE 0.125f                    // sqrt(0.125)/64^0.25 == 1/8 exactly
#define PHI_SCALE 0.08838834764831845f     // 1/sqrt(128)

typedef __attribute__((ext_vector_type(8))) short bf8;     // 8 bf16
typedef __attribute__((ext_vector_type(4))) short bf4;     // 4 bf16
typedef __attribute__((ext_vector_type(16))) float facc16; // 32x32 MFMA acc

static __device__ __forceinline__ unsigned short f2b(float f) {
    union { __hip_bfloat16 h; unsigned short u; } c;
    c.h = __float2bfloat16(f);                 // hw v_cvt (RNE), 1 op
    return c.u;
}
static __device__ __forceinline__ float b2f(unsigned short s) {
    return __uint_as_float(((unsigned)s) << 16);
}

// ============== kW: W -> WF (bf16, MFMA-B fragment order) ===================
// WF slot ((tile*4+s)*64 + hi*32 + lo)*8 + e  =  W[d=16s+8hi+e][r=32*tile+lo]
__global__ __launch_bounds__(256) void kW(const float* __restrict__ W,
                                          unsigned short* __restrict__ WF) {
    __shared__ float wl[8192];
    for (int i = threadIdx.x; i < 8192; i += 256) wl[i] = W[i];
    __syncthreads();
    for (int i = threadIdx.x; i < 1024; i += 256) {
        int tile = i >> 8, s = (i >> 6) & 3, hi = (i >> 5) & 1, lo = i & 31;
        int r = tile * 32 + lo;
        #pragma unroll
        for (int e = 0; e < 8; ++e)
            WF[i * 8 + e] = f2b(wl[(16 * s + 8 * hi + e) * 128 + r]);
    }
}

// ============== k1: 512-thr, 8 waves: phi_q, phi_k, vT, skv, zk =============
__global__ __launch_bounds__(512, 8) void k1(
    const float* __restrict__ q, const float* __restrict__ k,
    const float* __restrict__ v, const unsigned short* __restrict__ WF,
    unsigned short* __restrict__ pqF, unsigned short* __restrict__ pkF,
    unsigned short* __restrict__ vTF, unsigned short* __restrict__ skvTp,
    float* __restrict__ zk)
{
    __shared__ __align__(16) unsigned short A_[8192];  // pkT[r][c] swz8 (16KB)
    __shared__ __align__(16) unsigned short B_[4096];  // v linear swz8   (8KB)
    __shared__ __align__(16) unsigned short C_[8192];  // pq/pk swz16 -> vT swz8 (16KB)
    const int tid = threadIdx.x, hn = blockIdx.x;
    const int lane = tid & 63, w = tid >> 6, lo = lane & 31, hi = lane >> 5;
    const int rg = w & 1, ch = w >> 1;                 // rg in [0,2), ch in [0,4)
    const size_t cbase = (size_t)hn * C2 * D;

    // ---- phase 0: v -> B_ ; q A-frags + ssq ; phi_q MFMA -> C_ ----
    {
        int prow = tid >> 4, pd0 = (tid & 15) * 4;
        #pragma unroll
        for (int n = 0; n < 2; ++n) {
            int row = prow + 32 * n;
            float4 vv = *(const float4*)(v + cbase + row * 64 + pd0);
            unsigned* p = (unsigned*)&B_[(unsigned)((row * 64 + pd0) ^ ((row & 7) << 3))];
            p[0] = (unsigned)f2b(vv.x) | ((unsigned)f2b(vv.y) << 16);
            p[1] = (unsigned)f2b(vv.z) | ((unsigned)f2b(vv.w) << 16);
        }
    }
    bf8 af[4];
    float ssq = 0.f;
    #pragma unroll
    for (int s = 0; s < 4; ++s) {
        const float* qp = q + cbase + (rg * 32 + lo) * 64 + 16 * s + 8 * hi;
        float4 f0 = *(const float4*)qp;
        float4 f1 = *(const float4*)(qp + 4);
        float x0 = f0.x * XS_SCALE, x1 = f0.y * XS_SCALE, x2 = f0.z * XS_SCALE, x3 = f0.w * XS_SCALE;
        float x4 = f1.x * XS_SCALE, x5 = f1.y * XS_SCALE, x6 = f1.z * XS_SCALE, x7 = f1.w * XS_SCALE;
        ssq += x0*x0 + x1*x1 + x2*x2 + x3*x3 + x4*x4 + x5*x5 + x6*x6 + x7*x7;
        bf8 a;
        a[0]=(short)f2b(x0); a[1]=(short)f2b(x1); a[2]=(short)f2b(x2); a[3]=(short)f2b(x3);
        a[4]=(short)f2b(x4); a[5]=(short)f2b(x5); a[6]=(short)f2b(x6); a[7]=(short)f2b(x7);
        af[s] = a;
    }
    ssq += __shfl_xor(ssq, 32); ssq *= 0.5f;
    {
        facc16 acc;
        #pragma unroll
        for (int e = 0; e < 16; ++e) acc[e] = 0.f;
        #pragma unroll
        for (int s = 0; s < 4; ++s) {
            const bf8 b = *(const bf8*)(WF + ((ch * 4 + s) * 64 + hi * 32 + lo) * 8);
            acc = __builtin_amdgcn_mfma_f32_32x32x16_bf16(af[s], b, acc, 0, 0, 0);
        }
        #pragma unroll
        for (int reg = 0; reg < 16; ++reg) {
            int row = rg * 32 + (reg & 3) + 8 * (reg >> 2) + 4 * hi;
            int col = ch * 32 + lo;
            float sq = __shfl(ssq, (reg & 3) + 8 * (reg >> 2) + 4 * hi);
            C_[(unsigned)((row * 128 + col) ^ ((row & 15) << 3))] =
                f2b(__expf(acc[reg] - sq) * PHI_SCALE);
        }
    }
    __syncthreads();                                   // S1

    // ---- phase A: pq frag-dump; k A-frags + ssqk; phi_k MFMA ----
    #pragma unroll
    for (int s2 = 0; s2 < 2; ++s2) {
        int s = ch * 2 + s2;
        bf8 t8 = *(const bf8*)&C_[(unsigned)(((rg * 32 + lo) * 128 + 16 * s + 8 * hi) ^ ((lo & 15) << 3))];
        *(bf8*)(pqF + (size_t)hn * 8192 + (size_t)(((rg * 8 + s) * 64 + hi * 32 + lo) * 8)) = t8;
    }
    float ssqk = 0.f;
    #pragma unroll
    for (int s = 0; s < 4; ++s) {
        const float* kp = k + cbase + (rg * 32 + lo) * 64 + 16 * s + 8 * hi;
        float4 f0 = *(const float4*)kp;
        float4 f1 = *(const float4*)(kp + 4);
        float x0 = f0.x * XS_SCALE, x1 = f0.y * XS_SCALE, x2 = f0.z * XS_SCALE, x3 = f0.w * XS_SCALE;
        float x4 = f1.x * XS_SCALE, x5 = f1.y * XS_SCALE, x6 = f1.z * XS_SCALE, x7 = f1.w * XS_SCALE;
        ssqk += x0*x0 + x1*x1 + x2*x2 + x3*x3 + x4*x4 + x5*x5 + x6*x6 + x7*x7;
        bf8 a;
        a[0]=(short)f2b(x0); a[1]=(short)f2b(x1); a[2]=(short)f2b(x2); a[3]=(short)f2b(x3);
        a[4]=(short)f2b(x4); a[5]=(short)f2b(x5); a[6]=(short)f2b(x6); a[7]=(short)f2b(x7);
        af[s] = a;
    }
    ssqk += __shfl_xor(ssqk, 32); ssqk *= 0.5f;
    facc16 acck;
    #pragma unroll
    for (int e = 0; e < 16; ++e) acck[e] = 0.f;
    #pragma unroll
    for (int s = 0; s < 4; ++s) {
        const bf8 b = *(const bf8*)(WF + ((ch * 4 + s) * 64 + hi * 32 + lo) * 8);
        acck = __builtin_amdgcn_mfma_f32_32x32x16_bf16(af[s], b, acck, 0, 0, 0);
    }
    __syncthreads();                                   // S2 (pq-dump reads done)

    // ---- phase B: pk -> C_ swz16 ; pkT -> A_ swz8 ----
    {
        int colr = ch * 32 + lo;
        #pragma unroll
        for (int g = 0; g < 4; ++g) {
            int c0 = rg * 32 + 8 * g + 4 * hi;
            bf4 pk4;
            #pragma unroll
            for (int e = 0; e < 4; ++e) {
                float sq = __shfl(ssqk, 8 * g + 4 * hi + e);
                unsigned short bb = f2b(__expf(acck[4 * g + e] - sq) * PHI_SCALE);
                pk4[e] = (short)bb;
                C_[(unsigned)(((c0 + e) * 128 + colr) ^ (((c0 + e) & 15) << 3))] = bb;
            }
            *(bf4*)&A_[(unsigned)((colr * 64 + c0) ^ ((colr & 7) << 3))] = pk4;
        }
    }
    __syncthreads();                                   // S3

    // ---- phase C: pk frag-dump; zk MFMA (w<4) ; vT identity-MFMA (w>=4) ----
    #pragma unroll
    for (int s2 = 0; s2 < 2; ++s2) {
        int s = ch * 2 + s2;
        bf8 t8 = *(const bf8*)&C_[(unsigned)(((rg * 32 + lo) * 128 + 16 * s + 8 * hi) ^ ((lo & 15) << 3))];
        *(bf8*)(pkF + (size_t)hn * 8192 + (size_t)(((rg * 8 + s) * 64 + hi * 32 + lo) * 8)) = t8;
    }
    facc16 tv;
    if (w < 4) {                                       // zk[r] = rowsum(pkT)
        bf8 onesk;
        #pragma unroll
        for (int e = 0; e < 8; ++e) onesk[e] = (lo == 0) ? (short)0x3F80 : (short)0;
        facc16 az;
        #pragma unroll
        for (int e = 0; e < 16; ++e) az[e] = 0.f;
        #pragma unroll
        for (int s = 0; s < 4; ++s) {
            const bf8 a = *(const bf8*)&A_[(unsigned)(((w * 32 + lo) * 64 + 16 * s + 8 * hi) ^ ((lo & 7) << 3))];
            az = __builtin_amdgcn_mfma_f32_32x32x16_bf16(a, onesk, az, 0, 0, 0);
        }
        if (lo == 0) {
            #pragma unroll
            for (int reg = 0; reg < 16; ++reg)
                zk[(size_t)hn * 128 + w * 32 + (reg & 3) + 8 * (reg >> 2) + 4 * hi] = az[reg];
        }
    } else {                                           // vT tile (t,u)
        int t = (w - 4) >> 1, u = (w - 4) & 1;
        bf8 aid[2];
        #pragma unroll
        for (int s2 = 0; s2 < 2; ++s2)
            #pragma unroll
            for (int e = 0; e < 8; ++e)
                aid[s2][e] = (e == lo - 16 * s2 - 8 * hi) ? (short)0x3F80 : (short)0;
        #pragma unroll
        for (int e = 0; e < 16; ++e) tv[e] = 0.f;
        #pragma unroll
        for (int s2 = 0; s2 < 2; ++s2) {
            const bf8 b = *(const bf8*)&B_[(unsigned)(((32 * u + lo) * 64 + 16 * (2 * t + s2) + 8 * hi) ^ ((lo & 7) << 3))];
            tv = __builtin_amdgcn_mfma_f32_32x32x16_bf16(aid[s2], b, tv, 0, 0, 0);
        }
    }
    __syncthreads();                                   // S4 (pk-dump reads done)

    // ---- phase D: vT epilogue -> C_ [d][c] swz8 (waves 4-7) ----
    if (w >= 4) {
        int t = (w - 4) >> 1, u = (w - 4) & 1;
        #pragma unroll
        for (int reg = 0; reg < 16; ++reg) {
            int d = 32 * t + (reg & 3) + 8 * (reg >> 2) + 4 * hi;
            int c = 32 * u + lo;
            C_[(unsigned)((d * 64 + c) ^ ((d & 7) << 3))] = f2b(tv[reg]);
        }
    }
    __syncthreads();                                   // S5

    // ---- phase E: vT frag-dump; skv MFMA; skvTp dump ----
    {
        int g2 = w & 1, s = w >> 1;                    // 8 frag-sets, 1 per wave
        bf8 t8 = *(const bf8*)&C_[(unsigned)(((g2 * 32 + lo) * 64 + 16 * s + 8 * hi) ^ ((lo & 7) << 3))];
        *(bf8*)(vTF + (size_t)hn * 4096 + (size_t)(((g2 * 4 + s) * 64 + hi * 32 + lo) * 8)) = t8;
    }
    {
        facc16 acs;
        #pragma unroll
        for (int e = 0; e < 16; ++e) acs[e] = 0.f;
        int colr = ch * 32 + lo;
        #pragma unroll
        for (int s = 0; s < 4; ++s) {
            const bf8 a = *(const bf8*)&C_[(unsigned)(((rg * 32 + lo) * 64 + 16 * s + 8 * hi) ^ ((lo & 7) << 3))];
            const bf8 b = *(const bf8*)&A_[(unsigned)((colr * 64 + 16 * s + 8 * hi) ^ ((colr & 7) << 3))];
            acs = __builtin_amdgcn_mfma_f32_32x32x16_bf16(a, b, acs, 0, 0, 0);
        }
        unsigned short* sg = skvTp + (size_t)hn * 8192;
        #pragma unroll
        for (int reg = 0; reg < 16; ++reg) {
            int d = rg * 32 + (reg & 3) + 8 * (reg >> 2) + 4 * hi;
            sg[d * 128 + colr] = f2b(acs[reg]);
        }
    }
}

// ============== k2: pair-split exclusive scans (lanes 2i/2i+1 per column) ===
__global__ __launch_bounds__(256) void k2(unsigned short* __restrict__ skvTp,
                                          const float* __restrict__ zk,
                                          unsigned short* __restrict__ zkp)
{
    const int bid = blockIdx.x, tid = threadIdx.x;
    if (bid < 1024) {                                  // skv: 131072 cols x 2 halves
        int g = bid * 256 + tid;
        int cid = g >> 1, half = g & 1;
        int h = cid >> 13, dr = cid & 8191;
        unsigned short* p = skvTp + (size_t)h * NC2 * 8192 + (size_t)(half * 32) * 8192 + dr;
        unsigned short vals[32];
        #pragma unroll
        for (int n = 0; n < 32; ++n) vals[n] = p[(size_t)n * 8192];
        float T = 0.f;
        #pragma unroll
        for (int n = 0; n < 32; ++n) T += b2f(vals[n]);
        float off = __shfl_xor(T, 1);
        float run = half ? off : 0.f;
        #pragma unroll
        for (int n = 0; n < 32; ++n) {
            float t = b2f(vals[n]);
            p[(size_t)n * 8192] = f2b(run);
            run += t;
        }
    } else {                                           // zk: 2048 cols x 2 halves
        int g = (bid - 1024) * 256 + tid;
        int cid = g >> 1, half = g & 1;
        int h = cid >> 7, r = cid & 127;
        const float* pz = zk + (size_t)h * NC2 * 128 + half * 32 * 128 + r;
        unsigned short* oz = zkp + (size_t)h * NC2 * 128 + half * 32 * 128 + r;
        float vals[32];
        #pragma unroll
        for (int n = 0; n < 32; ++n) vals[n] = pz[n * 128];
        float T = 0.f;
        #pragma unroll
        for (int n = 0; n < 32; ++n) T += vals[n];
        float off = __shfl_xor(T, 1);
        float run = half ? off : 0.f;
        #pragma unroll
        for (int n = 0; n < 32; ++n) {
            oz[n * 128] = f2b(run);
            run += vals[n];
        }
    }
}

// ============== k3: GEMM1 + mask + num/den GEMM + divide (1 barrier) ========
__global__ __launch_bounds__(256) void k3(
    const unsigned short* __restrict__ pqF, const unsigned short* __restrict__ pkF,
    const unsigned short* __restrict__ vTF, const unsigned short* __restrict__ skvTp,
    const unsigned short* __restrict__ zkp, float* __restrict__ out)
{
    __shared__ __align__(16) unsigned short P_[8192];  // svl [d][r] swz16 (16KB)
    __shared__ __align__(16) unsigned short S_[4096];  // A_att [l][s] swz8 (8KB)
    const int tid = threadIdx.x, hn = blockIdx.x;
    const int lane = tid & 63, wave = tid >> 6, lo = lane & 31, hi = lane >> 5;
    const int rg = wave & 1, ch = wave >> 1;

    for (int i = tid; i < 1024; i += 256) {            // stage svl early
        bf8 t8 = *(const bf8*)(skvTp + (size_t)hn * 8192 + (size_t)i * 8);
        int d = i >> 4, r0 = (i & 15) * 8;
        *(bf8*)&P_[(unsigned)((d * 128 + r0) ^ ((d & 15) << 3))] = t8;
    }
    bf8 qf[8];
    #pragma unroll
    for (int s = 0; s < 8; ++s)
        qf[s] = *(const bf8*)(pqF + (size_t)hn * 8192 + (size_t)(((rg * 8 + s) * 64 + hi * 32 + lo) * 8));
    bf8 onesf, zf[8];
    #pragma unroll
    for (int e = 0; e < 8; ++e) onesf[e] = (lo == 0) ? (short)0x3F80 : (short)0;
    #pragma unroll
    for (int s = 0; s < 8; ++s)
        #pragma unroll
        for (int e = 0; e < 8; ++e) zf[s][e] = 0;
    if (lo == 0) {
        #pragma unroll
        for (int s = 0; s < 8; ++s)
            zf[s] = *(const bf8*)(zkp + (size_t)hn * 128 + 16 * s + 8 * hi);
    }

    facc16 ac1;                                        // GEMM1: A = pq.pk^T
    #pragma unroll
    for (int e = 0; e < 16; ++e) ac1[e] = 0.f;
    #pragma unroll
    for (int s = 0; s < 8; ++s) {
        const bf8 b = *(const bf8*)(pkF + (size_t)hn * 8192 + (size_t)(((ch * 8 + s) * 64 + hi * 32 + lo) * 8));
        ac1 = __builtin_amdgcn_mfma_f32_32x32x16_bf16(qf[s], b, ac1, 0, 0, 0);
    }
    #pragma unroll
    for (int reg = 0; reg < 16; ++reg) {               // masked A -> S_
        int row = rg * 32 + (reg & 3) + 8 * (reg >> 2) + 4 * hi;
        int sc = ch * 32 + lo;
        S_[(unsigned)((row * 64 + sc) ^ ((row & 7) << 3))] = f2b(sc < row ? ac1[reg] : 0.f);
    }
    __syncthreads();                                   // S1 (A_att + svl visible)

    facc16 an, ad;
    #pragma unroll
    for (int e = 0; e < 16; ++e) { an[e] = 0.f; ad[e] = 0.f; }
    #pragma unroll
    for (int s = 0; s < 4; ++s) {                      // pass A: k = c
        const bf8 a = *(const bf8*)&S_[(unsigned)(((rg * 32 + lo) * 64 + 16 * s + 8 * hi) ^ ((lo & 7) << 3))];
        const bf8 b = *(const bf8*)(vTF + (size_t)hn * 4096 + (size_t)(((ch * 4 + s) * 64 + hi * 32 + lo) * 8));
        an = __builtin_amdgcn_mfma_f32_32x32x16_bf16(a, b, an, 0, 0, 0);
        ad = __builtin_amdgcn_mfma_f32_32x32x16_bf16(a, onesf, ad, 0, 0, 0);
    }
    #pragma unroll
    for (int s = 0; s < 8; ++s) {                      // pass B: k = r
        const bf8 b = *(const bf8*)&P_[(unsigned)(((ch * 32 + lo) * 128 + 16 * s + 8 * hi) ^ ((lo & 15) << 3))];
        an = __builtin_amdgcn_mfma_f32_32x32x16_bf16(qf[s], b, an, 0, 0, 0);
        ad = __builtin_amdgcn_mfma_f32_32x32x16_bf16(qf[s], zf[s], ad, 0, 0, 0);
    }
    float* og = out + (size_t)hn * C2 * D;
    #pragma unroll
    for (int reg = 0; reg < 16; ++reg) {
        int row = rg * 32 + (reg & 3) + 8 * (reg >> 2) + 4 * hi;
        float dv = __shfl(ad[reg], lane & 32);
        og[row * 64 + ch * 32 + lo] = an[reg] / (dv + EPS);
    }
}

// ---------------------------------------------------------------------------
extern "C" void kernel_launch(void* const* d_in, const int* in_sizes, int n_in,
                              void* d_out, int out_size, void* d_ws, size_t ws_size,
                              hipStream_t stream) {
    // setup_inputs order: {T, k, q, v, W}
    const float* k = (const float*)d_in[1];
    const float* q = (const float*)d_in[2];
    const float* v = (const float*)d_in[3];
    const float* W = (const float*)d_in[4];
    float* out = (float*)d_out;

    // ws (u16 units): pqF 16MB | pkF 16MB | vTF 8MB | skvTp 16MB | WF | zkp | zk
    unsigned short* pqF   = (unsigned short*)d_ws;
    unsigned short* pkF   = pqF + (size_t)HN2 * 8192;
    unsigned short* vTF   = pkF + (size_t)HN2 * 8192;
    unsigned short* skvTp = vTF + (size_t)HN2 * 4096;
    unsigned short* WF    = skvTp + (size_t)HN2 * 8192;
    unsigned short* zkp   = WF + 8192;
    float* zk             = (float*)(zkp + (size_t)HN2 * 128);

    kW<<<1, 256, 0, stream>>>(W, WF);
    k1<<<HN2, 512, 0, stream>>>(q, k, v, WF, pqF, pkF, vTF, skvTp, zk);
    k2<<<1040, 256, 0, stream>>>(skvTp, zk, zkp);
    k3<<<HN2, 256, 0, stream>>>(pqF, pkF, vTF, skvTp, zkp, out);
}

// Round 11
// 68.218 us; speedup vs baseline: 1.1246x; 1.1246x over previous
//
#include <hip/hip_runtime.h>
#include <hip/hip_bf16.h>

#define H 16
#define L 4096
#define D 64
#define R 128
#define C2 64
#define NC2 64
#define HN2 (H * NC2)      // 1024 chunks
#define EPS 1e-10f
#define XS_SCALE 0.125f                    // sqrt(0.125)/64^0.25 == 1/8 exactly
#define PHI_SCALE 0.08838834764831845f     // 1/sqrt(128)

typedef __attribute__((ext_vector_type(8))) short bf8;     // 8 bf16
typedef __attribute__((ext_vector_type(4))) short bf4;     // 4 bf16
typedef __attribute__((ext_vector_type(16))) float facc16; // 32x32 MFMA acc

static __device__ __forceinline__ unsigned short f2b(float f) {
    union { __hip_bfloat16 h; unsigned short u; } c;
    c.h = __float2bfloat16(f);                 // hw v_cvt (RNE), 1 op
    return c.u;
}
static __device__ __forceinline__ float b2f(unsigned short s) {
    return __uint_as_float(((unsigned)s) << 16);
}

// ============== kW: W -> WF (bf16, MFMA-B fragment order) ===================
// WF slot ((tile*4+s)*64 + hi*32 + lo)*8 + e  =  W[d=16s+8hi+e][r=32*tile+lo]
__global__ __launch_bounds__(256) void kW(const float* __restrict__ W,
                                          unsigned short* __restrict__ WF) {
    __shared__ float wl[8192];
    for (int i = threadIdx.x; i < 8192; i += 256) wl[i] = W[i];
    __syncthreads();
    for (int i = threadIdx.x; i < 1024; i += 256) {
        int tile = i >> 8, s = (i >> 6) & 3, hi = (i >> 5) & 1, lo = i & 31;
        int r = tile * 32 + lo;
        #pragma unroll
        for (int e = 0; e < 8; ++e)
            WF[i * 8 + e] = f2b(wl[(16 * s + 8 * hi + e) * 128 + r]);
    }
}

// ============== k1: 512-thr, 8 waves, 128-VGPR budget =======================
__global__ __launch_bounds__(512, 4) void k1(
    const float* __restrict__ q, const float* __restrict__ k,
    const float* __restrict__ v, const unsigned short* __restrict__ WF,
    unsigned short* __restrict__ pqF, unsigned short* __restrict__ pkF,
    unsigned short* __restrict__ vTF, unsigned short* __restrict__ skvTp,
    float* __restrict__ zk)
{
    __shared__ __align__(16) unsigned short A_[8192];  // pkT[r][c] swz8 (16KB)
    __shared__ __align__(16) unsigned short B_[4096];  // v linear swz8   (8KB)
    __shared__ __align__(16) unsigned short C_[8192];  // pq/pk swz16 -> vT swz8 (16KB)
    const int tid = threadIdx.x, hn = blockIdx.x;
    const int lane = tid & 63, w = tid >> 6, lo = lane & 31, hi = lane >> 5;
    const int rg = w & 1, ch = w >> 1;                 // rg in [0,2), ch in [0,4)
    const size_t cbase = (size_t)hn * C2 * D;

    // ---- phase 0: v -> B_ ; q A-frags + ssq ; phi_q MFMA -> C_ ----
    {
        int prow = tid >> 4, pd0 = (tid & 15) * 4;
        #pragma unroll
        for (int n = 0; n < 2; ++n) {
            int row = prow + 32 * n;
            float4 vv = *(const float4*)(v + cbase + row * 64 + pd0);
            unsigned* p = (unsigned*)&B_[(unsigned)((row * 64 + pd0) ^ ((row & 7) << 3))];
            p[0] = (unsigned)f2b(vv.x) | ((unsigned)f2b(vv.y) << 16);
            p[1] = (unsigned)f2b(vv.z) | ((unsigned)f2b(vv.w) << 16);
        }
    }
    bf8 af[4];
    float ssq = 0.f;
    #pragma unroll
    for (int s = 0; s < 4; ++s) {
        const float* qp = q + cbase + (rg * 32 + lo) * 64 + 16 * s + 8 * hi;
        float4 f0 = *(const float4*)qp;
        float4 f1 = *(const float4*)(qp + 4);
        float x0 = f0.x * XS_SCALE, x1 = f0.y * XS_SCALE, x2 = f0.z * XS_SCALE, x3 = f0.w * XS_SCALE;
        float x4 = f1.x * XS_SCALE, x5 = f1.y * XS_SCALE, x6 = f1.z * XS_SCALE, x7 = f1.w * XS_SCALE;
        ssq += x0*x0 + x1*x1 + x2*x2 + x3*x3 + x4*x4 + x5*x5 + x6*x6 + x7*x7;
        bf8 a;
        a[0]=(short)f2b(x0); a[1]=(short)f2b(x1); a[2]=(short)f2b(x2); a[3]=(short)f2b(x3);
        a[4]=(short)f2b(x4); a[5]=(short)f2b(x5); a[6]=(short)f2b(x6); a[7]=(short)f2b(x7);
        af[s] = a;
    }
    ssq += __shfl_xor(ssq, 32); ssq *= 0.5f;
    {
        facc16 acc;
        #pragma unroll
        for (int e = 0; e < 16; ++e) acc[e] = 0.f;
        #pragma unroll
        for (int s = 0; s < 4; ++s) {
            const bf8 b = *(const bf8*)(WF + ((ch * 4 + s) * 64 + hi * 32 + lo) * 8);
            acc = __builtin_amdgcn_mfma_f32_32x32x16_bf16(af[s], b, acc, 0, 0, 0);
        }
        #pragma unroll
        for (int reg = 0; reg < 16; ++reg) {
            int row = rg * 32 + (reg & 3) + 8 * (reg >> 2) + 4 * hi;
            int col = ch * 32 + lo;
            float sq = __shfl(ssq, (reg & 3) + 8 * (reg >> 2) + 4 * hi);
            C_[(unsigned)((row * 128 + col) ^ ((row & 15) << 3))] =
                f2b(__expf(acc[reg] - sq) * PHI_SCALE);
        }
    }
    __syncthreads();                                   // S1

    // ---- phase A: pq frag-dump; k A-frags + ssqk; phi_k MFMA ----
    #pragma unroll
    for (int s2 = 0; s2 < 2; ++s2) {
        int s = ch * 2 + s2;
        bf8 t8 = *(const bf8*)&C_[(unsigned)(((rg * 32 + lo) * 128 + 16 * s + 8 * hi) ^ ((lo & 15) << 3))];
        *(bf8*)(pqF + (size_t)hn * 8192 + (size_t)(((rg * 8 + s) * 64 + hi * 32 + lo) * 8)) = t8;
    }
    float ssqk = 0.f;
    #pragma unroll
    for (int s = 0; s < 4; ++s) {
        const float* kp = k + cbase + (rg * 32 + lo) * 64 + 16 * s + 8 * hi;
        float4 f0 = *(const float4*)kp;
        float4 f1 = *(const float4*)(kp + 4);
        float x0 = f0.x * XS_SCALE, x1 = f0.y * XS_SCALE, x2 = f0.z * XS_SCALE, x3 = f0.w * XS_SCALE;
        float x4 = f1.x * XS_SCALE, x5 = f1.y * XS_SCALE, x6 = f1.z * XS_SCALE, x7 = f1.w * XS_SCALE;
        ssqk += x0*x0 + x1*x1 + x2*x2 + x3*x3 + x4*x4 + x5*x5 + x6*x6 + x7*x7;
        bf8 a;
        a[0]=(short)f2b(x0); a[1]=(short)f2b(x1); a[2]=(short)f2b(x2); a[3]=(short)f2b(x3);
        a[4]=(short)f2b(x4); a[5]=(short)f2b(x5); a[6]=(short)f2b(x6); a[7]=(short)f2b(x7);
        af[s] = a;
    }
    ssqk += __shfl_xor(ssqk, 32); ssqk *= 0.5f;
    facc16 acck;
    #pragma unroll
    for (int e = 0; e < 16; ++e) acck[e] = 0.f;
    #pragma unroll
    for (int s = 0; s < 4; ++s) {
        const bf8 b = *(const bf8*)(WF + ((ch * 4 + s) * 64 + hi * 32 + lo) * 8);
        acck = __builtin_amdgcn_mfma_f32_32x32x16_bf16(af[s], b, acck, 0, 0, 0);
    }
    __syncthreads();                                   // S2 (pq-dump reads done)

    // ---- phase B: pk -> C_ swz16 ; pkT -> A_ swz8 ----
    {
        int colr = ch * 32 + lo;
        #pragma unroll
        for (int g = 0; g < 4; ++g) {
            int c0 = rg * 32 + 8 * g + 4 * hi;
            bf4 pk4;
            #pragma unroll
            for (int e = 0; e < 4; ++e) {
                float sq = __shfl(ssqk, 8 * g + 4 * hi + e);
                unsigned short bb = f2b(__expf(acck[4 * g + e] - sq) * PHI_SCALE);
                pk4[e] = (short)bb;
                C_[(unsigned)(((c0 + e) * 128 + colr) ^ (((c0 + e) & 15) << 3))] = bb;
            }
            *(bf4*)&A_[(unsigned)((colr * 64 + c0) ^ ((colr & 7) << 3))] = pk4;
        }
    }
    __syncthreads();                                   // S3

    // ---- phase C: pk frag-dump; zk MFMA (w<4) ; vT identity-MFMA (w>=4) ----
    #pragma unroll
    for (int s2 = 0; s2 < 2; ++s2) {
        int s = ch * 2 + s2;
        bf8 t8 = *(const bf8*)&C_[(unsigned)(((rg * 32 + lo) * 128 + 16 * s + 8 * hi) ^ ((lo & 15) << 3))];
        *(bf8*)(pkF + (size_t)hn * 8192 + (size_t)(((rg * 8 + s) * 64 + hi * 32 + lo) * 8)) = t8;
    }
    facc16 tv;
    if (w < 4) {                                       // zk[r] = rowsum(pkT)
        bf8 onesk;
        #pragma unroll
        for (int e = 0; e < 8; ++e) onesk[e] = (lo == 0) ? (short)0x3F80 : (short)0;
        facc16 az;
        #pragma unroll
        for (int e = 0; e < 16; ++e) az[e] = 0.f;
        #pragma unroll
        for (int s = 0; s < 4; ++s) {
            const bf8 a = *(const bf8*)&A_[(unsigned)(((w * 32 + lo) * 64 + 16 * s + 8 * hi) ^ ((lo & 7) << 3))];
            az = __builtin_amdgcn_mfma_f32_32x32x16_bf16(a, onesk, az, 0, 0, 0);
        }
        if (lo == 0) {
            #pragma unroll
            for (int reg = 0; reg < 16; ++reg)
                zk[(size_t)hn * 128 + w * 32 + (reg & 3) + 8 * (reg >> 2) + 4 * hi] = az[reg];
        }
    } else {                                           // vT tile (t,u)
        int t = (w - 4) >> 1, u = (w - 4) & 1;
        bf8 aid[2];
        #pragma unroll
        for (int s2 = 0; s2 < 2; ++s2)
            #pragma unroll
            for (int e = 0; e < 8; ++e)
                aid[s2][e] = (e == lo - 16 * s2 - 8 * hi) ? (short)0x3F80 : (short)0;
        #pragma unroll
        for (int e = 0; e < 16; ++e) tv[e] = 0.f;
        #pragma unroll
        for (int s2 = 0; s2 < 2; ++s2) {
            const bf8 b = *(const bf8*)&B_[(unsigned)(((32 * u + lo) * 64 + 16 * (2 * t + s2) + 8 * hi) ^ ((lo & 7) << 3))];
            tv = __builtin_amdgcn_mfma_f32_32x32x16_bf16(aid[s2], b, tv, 0, 0, 0);
        }
    }
    __syncthreads();                                   // S4 (pk-dump reads done)

    // ---- phase D: vT epilogue -> C_ [d][c] swz8 (waves 4-7) ----
    if (w >= 4) {
        int t = (w - 4) >> 1, u = (w - 4) & 1;
        #pragma unroll
        for (int reg = 0; reg < 16; ++reg) {
            int d = 32 * t + (reg & 3) + 8 * (reg >> 2) + 4 * hi;
            int c = 32 * u + lo;
            C_[(unsigned)((d * 64 + c) ^ ((d & 7) << 3))] = f2b(tv[reg]);
        }
    }
    __syncthreads();                                   // S5

    // ---- phase E: vT frag-dump; skv MFMA; skvTp dump ----
    {
        int g2 = w & 1, s = w >> 1;                    // 8 frag-sets, 1 per wave
        bf8 t8 = *(const bf8*)&C_[(unsigned)(((g2 * 32 + lo) * 64 + 16 * s + 8 * hi) ^ ((lo & 7) << 3))];
        *(bf8*)(vTF + (size_t)hn * 4096 + (size_t)(((g2 * 4 + s) * 64 + hi * 32 + lo) * 8)) = t8;
    }
    {
        facc16 acs;
        #pragma unroll
        for (int e = 0; e < 16; ++e) acs[e] = 0.f;
        int colr = ch * 32 + lo;
        #pragma unroll
        for (int s = 0; s < 4; ++s) {
            const bf8 a = *(const bf8*)&C_[(unsigned)(((rg * 32 + lo) * 64 + 16 * s + 8 * hi) ^ ((lo & 7) << 3))];
            const bf8 b = *(const bf8*)&A_[(unsigned)((colr * 64 + 16 * s + 8 * hi) ^ ((colr & 7) << 3))];
            acs = __builtin_amdgcn_mfma_f32_32x32x16_bf16(a, b, acs, 0, 0, 0);
        }
        unsigned short* sg = skvTp + (size_t)hn * 8192;
        #pragma unroll
        for (int reg = 0; reg < 16; ++reg) {
            int d = rg * 32 + (reg & 3) + 8 * (reg >> 2) + 4 * hi;
            sg[d * 128 + colr] = f2b(acs[reg]);
        }
    }
}

// ============== k2: pair-split exclusive scans (lanes 2i/2i+1 per column) ===
__global__ __launch_bounds__(256) void k2(unsigned short* __restrict__ skvTp,
                                          const float* __restrict__ zk,
                                          unsigned short* __restrict__ zkp)
{
    const int bid = blockIdx.x, tid = threadIdx.x;
    if (bid < 1024) {                                  // skv: 131072 cols x 2 halves
        int g = bid * 256 + tid;
        int cid = g >> 1, half = g & 1;
        int h = cid >> 13, dr = cid & 8191;
        unsigned short* p = skvTp + (size_t)h * NC2 * 8192 + (size_t)(half * 32) * 8192 + dr;
        unsigned short vals[32];
        #pragma unroll
        for (int n = 0; n < 32; ++n) vals[n] = p[(size_t)n * 8192];
        float T = 0.f;
        #pragma unroll
        for (int n = 0; n < 32; ++n) T += b2f(vals[n]);
        float off = __shfl_xor(T, 1);
        float run = half ? off : 0.f;
        #pragma unroll
        for (int n = 0; n < 32; ++n) {
            float t = b2f(vals[n]);
            p[(size_t)n * 8192] = f2b(run);
            run += t;
        }
    } else {                                           // zk: 2048 cols x 2 halves
        int g = (bid - 1024) * 256 + tid;
        int cid = g >> 1, half = g & 1;
        int h = cid >> 7, r = cid & 127;
        const float* pz = zk + (size_t)h * NC2 * 128 + half * 32 * 128 + r;
        unsigned short* oz = zkp + (size_t)h * NC2 * 128 + half * 32 * 128 + r;
        float vals[32];
        #pragma unroll
        for (int n = 0; n < 32; ++n) vals[n] = pz[n * 128];
        float T = 0.f;
        #pragma unroll
        for (int n = 0; n < 32; ++n) T += vals[n];
        float off = __shfl_xor(T, 1);
        float run = half ? off : 0.f;
        #pragma unroll
        for (int n = 0; n < 32; ++n) {
            oz[n * 128] = f2b(run);
            run += vals[n];
        }
    }
}

// ============== k3: GEMM1 + mask + num/den GEMM + divide (1 barrier) ========
__global__ __launch_bounds__(256) void k3(
    const unsigned short* __restrict__ pqF, const unsigned short* __restrict__ pkF,
    const unsigned short* __restrict__ vTF, const unsigned short* __restrict__ skvTp,
    const unsigned short* __restrict__ zkp, float* __restrict__ out)
{
    __shared__ __align__(16) unsigned short P_[8192];  // svl [d][r] swz16 (16KB)
    __shared__ __align__(16) unsigned short S_[4096];  // A_att [l][s] swz8 (8KB)
    const int tid = threadIdx.x, hn = blockIdx.x;
    const int lane = tid & 63, wave = tid >> 6, lo = lane & 31, hi = lane >> 5;
    const int rg = wave & 1, ch = wave >> 1;

    for (int i = tid; i < 1024; i += 256) {            // stage svl early
        bf8 t8 = *(const bf8*)(skvTp + (size_t)hn * 8192 + (size_t)i * 8);
        int d = i >> 4, r0 = (i & 15) * 8;
        *(bf8*)&P_[(unsigned)((d * 128 + r0) ^ ((d & 15) << 3))] = t8;
    }
    bf8 qf[8];
    #pragma unroll
    for (int s = 0; s < 8; ++s)
        qf[s] = *(const bf8*)(pqF + (size_t)hn * 8192 + (size_t)(((rg * 8 + s) * 64 + hi * 32 + lo) * 8));
    bf8 onesf, zf[8];
    #pragma unroll
    for (int e = 0; e < 8; ++e) onesf[e] = (lo == 0) ? (short)0x3F80 : (short)0;
    #pragma unroll
    for (int s = 0; s < 8; ++s)
        #pragma unroll
        for (int e = 0; e < 8; ++e) zf[s][e] = 0;
    if (lo == 0) {
        #pragma unroll
        for (int s = 0; s < 8; ++s)
            zf[s] = *(const bf8*)(zkp + (size_t)hn * 128 + 16 * s + 8 * hi);
    }

    facc16 ac1;                                        // GEMM1: A = pq.pk^T
    #pragma unroll
    for (int e = 0; e < 16; ++e) ac1[e] = 0.f;
    #pragma unroll
    for (int s = 0; s < 8; ++s) {
        const bf8 b = *(const bf8*)(pkF + (size_t)hn * 8192 + (size_t)(((ch * 8 + s) * 64 + hi * 32 + lo) * 8));
        ac1 = __builtin_amdgcn_mfma_f32_32x32x16_bf16(qf[s], b, ac1, 0, 0, 0);
    }
    #pragma unroll
    for (int reg = 0; reg < 16; ++reg) {               // masked A -> S_
        int row = rg * 32 + (reg & 3) + 8 * (reg >> 2) + 4 * hi;
        int sc = ch * 32 + lo;
        S_[(unsigned)((row * 64 + sc) ^ ((row & 7) << 3))] = f2b(sc < row ? ac1[reg] : 0.f);
    }
    __syncthreads();                                   // S1 (A_att + svl visible)

    facc16 an, ad;
    #pragma unroll
    for (int e = 0; e < 16; ++e) { an[e] = 0.f; ad[e] = 0.f; }
    #pragma unroll
    for (int s = 0; s < 4; ++s) {                      // pass A: k = c
        const bf8 a = *(const bf8*)&S_[(unsigned)(((rg * 32 + lo) * 64 + 16 * s + 8 * hi) ^ ((lo & 7) << 3))];
        const bf8 b = *(const bf8*)(vTF + (size_t)hn * 4096 + (size_t)(((ch * 4 + s) * 64 + hi * 32 + lo) * 8));
        an = __builtin_amdgcn_mfma_f32_32x32x16_bf16(a, b, an, 0, 0, 0);
        ad = __builtin_amdgcn_mfma_f32_32x32x16_bf16(a, onesf, ad, 0, 0, 0);
    }
    #pragma unroll
    for (int s = 0; s < 8; ++s) {                      // pass B: k = r
        const bf8 b = *(const bf8*)&P_[(unsigned)(((ch * 32 + lo) * 128 + 16 * s + 8 * hi) ^ ((lo & 15) << 3))];
        an = __builtin_amdgcn_mfma_f32_32x32x16_bf16(qf[s], b, an, 0, 0, 0);
        ad = __builtin_amdgcn_mfma_f32_32x32x16_bf16(qf[s], zf[s], ad, 0, 0, 0);
    }
    float* og = out + (size_t)hn * C2 * D;
    #pragma unroll
    for (int reg = 0; reg < 16; ++reg) {
        int row = rg * 32 + (reg & 3) + 8 * (reg >> 2) + 4 * hi;
        float dv = __shfl(ad[reg], lane & 32);
        og[row * 64 + ch * 32 + lo] = an[reg] / (dv + EPS);
    }
}

// ---------------------------------------------------------------------------
extern "C" void kernel_launch(void* const* d_in, const int* in_sizes, int n_in,
                              void* d_out, int out_size, void* d_ws, size_t ws_size,
                              hipStream_t stream) {
    // setup_inputs order: {T, k, q, v, W}
    const float* k = (const float*)d_in[1];
    const float* q = (const float*)d_in[2];
    const float* v = (const float*)d_in[3];
    const float* W = (const float*)d_in[4];
    float* out = (float*)d_out;

    // ws (u16 units): pqF 16MB | pkF 16MB | vTF 8MB | skvTp 16MB | WF | zkp | zk
    unsigned short* pqF   = (unsigned short*)d_ws;
    unsigned short* pkF   = pqF + (size_t)HN2 * 8192;
    unsigned short* vTF   = pkF + (size_t)HN2 * 8192;
    unsigned short* skvTp = vTF + (size_t)HN2 * 4096;
    unsigned short* WF    = skvTp + (size_t)HN2 * 8192;
    unsigned short* zkp   = WF + 8192;
    float* zk             = (float*)(zkp + (size_t)HN2 * 128);

    kW<<<1, 256, 0, stream>>>(W, WF);
    k1<<<HN2, 512, 0, stream>>>(q, k, v, WF, pqF, pkF, vTF, skvTp, zk);
    k2<<<1040, 256, 0, stream>>>(skvTp, zk, zkp);
    k3<<<HN2, 256, 0, stream>>>(pqF, pkF, vTF, skvTp, zkp, out);
}

// Round 12
// 65.585 us; speedup vs baseline: 1.1698x; 1.0401x over previous
//
#include <hip/hip_runtime.h>
#include <hip/hip_bf16.h>

#define H 16
#define L 4096
#define D 64
#define R 128
#define C2 64
#define NC2 64
#define HN2 (H * NC2)      // 1024 chunks
#define EPS 1e-10f
#define XS_SCALE 0.125f                    // sqrt(0.125)/64^0.25 == 1/8 exactly
#define PHI_SCALE 0.08838834764831845f     // 1/sqrt(128)

typedef __attribute__((ext_vector_type(8))) short bf8;     // 8 bf16
typedef __attribute__((ext_vector_type(4))) short bf4;     // 4 bf16
typedef __attribute__((ext_vector_type(16))) float facc16; // 32x32 MFMA acc

static __device__ __forceinline__ unsigned short f2b(float f) {
    union { __hip_bfloat16 h; unsigned short u; } c;
    c.h = __float2bfloat16(f);                 // hw v_cvt (RNE), 1 op
    return c.u;
}
static __device__ __forceinline__ float b2f(unsigned short s) {
    return __uint_as_float(((unsigned)s) << 16);
}

// ============== kW: W -> WF (bf16, MFMA-B fragment order) ===================
// WF slot ((tile*4+s)*64 + hi*32 + lo)*8 + e  =  W[d=16s+8hi+e][r=32*tile+lo]
__global__ __launch_bounds__(256) void kW(const float* __restrict__ W,
                                          unsigned short* __restrict__ WF) {
    __shared__ float wl[8192];
    for (int i = threadIdx.x; i < 8192; i += 256) wl[i] = W[i];
    __syncthreads();
    for (int i = threadIdx.x; i < 1024; i += 256) {
        int tile = i >> 8, s = (i >> 6) & 3, hi = (i >> 5) & 1, lo = i & 31;
        int r = tile * 32 + lo;
        #pragma unroll
        for (int e = 0; e < 8; ++e)
            WF[i * 8 + e] = f2b(wl[(16 * s + 8 * hi + e) * 128 + r]);
    }
}

// ============== k1: phi_q, phi_k, vT, skv, zk — frag-layout dumps ===========
// R9 structure (256 thr, 4 waves, 40KB LDS) + k-chunk prefetch in phase 0.
__global__ __launch_bounds__(256, 4) void k1(
    const float* __restrict__ q, const float* __restrict__ k,
    const float* __restrict__ v, const unsigned short* __restrict__ WF,
    unsigned short* __restrict__ pqF, unsigned short* __restrict__ pkF,
    unsigned short* __restrict__ vTF, unsigned short* __restrict__ skvTp,
    float* __restrict__ zk)
{
    __shared__ __align__(16) unsigned short A_[8192];  // pkT[r][c] swz8 (16KB)
    __shared__ __align__(16) unsigned short B_[4096];  // v linear swz8   (8KB)
    __shared__ __align__(16) unsigned short C_[8192];  // pq/pk swz16 -> vT swz8 (16KB)
    const int tid = threadIdx.x, hn = blockIdx.x;
    const int lane = tid & 63, wave = tid >> 6, lo = lane & 31, hi = lane >> 5;
    const int rg = wave & 1, ch = wave >> 1;
    const size_t cbase = (size_t)hn * C2 * D;
    const int prow = tid >> 4, pd0 = (tid & 15) * 4;

    // ---- phase 0: v -> B_ ; q A-frags + ssq ; k prefetch ; phi_q MFMA ----
    #pragma unroll
    for (int n = 0; n < 4; ++n) {                      // v -> B_ linear swz8
        int row = prow + 16 * n;
        float4 vv = *(const float4*)(v + cbase + row * 64 + pd0);
        unsigned* p = (unsigned*)&B_[(unsigned)((row * 64 + pd0) ^ ((row & 7) << 3))];
        p[0] = (unsigned)f2b(vv.x) | ((unsigned)f2b(vv.y) << 16);
        p[1] = (unsigned)f2b(vv.z) | ((unsigned)f2b(vv.w) << 16);
    }
    bf8 af[4];
    float sqrow[16];
    {
        float ssq = 0.f;
        #pragma unroll
        for (int s = 0; s < 4; ++s) {
            const float* qp = q + cbase + (rg * 32 + lo) * 64 + 16 * s + 8 * hi;
            float4 f0 = *(const float4*)qp;
            float4 f1 = *(const float4*)(qp + 4);
            float x0 = f0.x * XS_SCALE, x1 = f0.y * XS_SCALE, x2 = f0.z * XS_SCALE, x3 = f0.w * XS_SCALE;
            float x4 = f1.x * XS_SCALE, x5 = f1.y * XS_SCALE, x6 = f1.z * XS_SCALE, x7 = f1.w * XS_SCALE;
            ssq += x0*x0 + x1*x1 + x2*x2 + x3*x3 + x4*x4 + x5*x5 + x6*x6 + x7*x7;
            bf8 a;
            a[0]=(short)f2b(x0); a[1]=(short)f2b(x1); a[2]=(short)f2b(x2); a[3]=(short)f2b(x3);
            a[4]=(short)f2b(x4); a[5]=(short)f2b(x5); a[6]=(short)f2b(x6); a[7]=(short)f2b(x7);
            af[s] = a;
        }
        ssq += __shfl_xor(ssq, 32); ssq *= 0.5f;
        #pragma unroll
        for (int r2 = 0; r2 < 16; ++r2)
            sqrow[r2] = __shfl(ssq, (r2 & 3) + 8 * (r2 >> 2) + 4 * hi);
    }
    float4 kv[8];                                      // k-chunk prefetch (T14)
    #pragma unroll
    for (int s = 0; s < 4; ++s) {
        const float* kp = k + cbase + (rg * 32 + lo) * 64 + 16 * s + 8 * hi;
        kv[2 * s]     = *(const float4*)kp;
        kv[2 * s + 1] = *(const float4*)(kp + 4);
    }
    {   // phi_q MFMA (B-frags from WF global) -> C_ pq[c][r] swz16
        facc16 acc[2];
        #pragma unroll
        for (int t = 0; t < 2; ++t)
            #pragma unroll
            for (int e = 0; e < 16; ++e) acc[t][e] = 0.f;
        #pragma unroll
        for (int s = 0; s < 4; ++s)
            #pragma unroll
            for (int t = 0; t < 2; ++t) {
                const bf8 b = *(const bf8*)(WF + (((2 * ch + t) * 4 + s) * 64 + hi * 32 + lo) * 8);
                acc[t] = __builtin_amdgcn_mfma_f32_32x32x16_bf16(af[s], b, acc[t], 0, 0, 0);
            }
        #pragma unroll
        for (int t = 0; t < 2; ++t)
            #pragma unroll
            for (int reg = 0; reg < 16; ++reg) {
                int row = rg * 32 + (reg & 3) + 8 * (reg >> 2) + 4 * hi;
                int col = (2 * ch + t) * 32 + lo;
                C_[(unsigned)((row * 128 + col) ^ ((row & 15) << 3))] =
                    f2b(__expf(acc[t][reg] - sqrow[reg]) * PHI_SCALE);
            }
    }
    __syncthreads();                                   // S1

    // ---- phase A: pq frag-dump; k convert (prefetched); phi_k MFMA ----
    {
        int g2 = wave & 1, sh = wave >> 1;
        #pragma unroll
        for (int s2 = 0; s2 < 4; ++s2) {
            int s = sh * 4 + s2;
            bf8 t8 = *(const bf8*)&C_[(unsigned)(((g2 * 32 + lo) * 128 + 16 * s + 8 * hi) ^ ((lo & 15) << 3))];
            *(bf8*)(pqF + (size_t)hn * 8192 + (size_t)(((g2 * 8 + s) * 64 + hi * 32 + lo) * 8)) = t8;
        }
    }
    float sqk[16];
    {
        float ssq = 0.f;
        #pragma unroll
        for (int s = 0; s < 4; ++s) {
            float4 f0 = kv[2 * s], f1 = kv[2 * s + 1];
            float x0 = f0.x * XS_SCALE, x1 = f0.y * XS_SCALE, x2 = f0.z * XS_SCALE, x3 = f0.w * XS_SCALE;
            float x4 = f1.x * XS_SCALE, x5 = f1.y * XS_SCALE, x6 = f1.z * XS_SCALE, x7 = f1.w * XS_SCALE;
            ssq += x0*x0 + x1*x1 + x2*x2 + x3*x3 + x4*x4 + x5*x5 + x6*x6 + x7*x7;
            bf8 a;
            a[0]=(short)f2b(x0); a[1]=(short)f2b(x1); a[2]=(short)f2b(x2); a[3]=(short)f2b(x3);
            a[4]=(short)f2b(x4); a[5]=(short)f2b(x5); a[6]=(short)f2b(x6); a[7]=(short)f2b(x7);
            af[s] = a;
        }
        ssq += __shfl_xor(ssq, 32); ssq *= 0.5f;
        #pragma unroll
        for (int r2 = 0; r2 < 16; ++r2)
            sqk[r2] = __shfl(ssq, (r2 & 3) + 8 * (r2 >> 2) + 4 * hi);
    }
    facc16 acck[2];
    #pragma unroll
    for (int t = 0; t < 2; ++t)
        #pragma unroll
        for (int e = 0; e < 16; ++e) acck[t][e] = 0.f;
    #pragma unroll
    for (int s = 0; s < 4; ++s)
        #pragma unroll
        for (int t = 0; t < 2; ++t) {
            const bf8 b = *(const bf8*)(WF + (((2 * ch + t) * 4 + s) * 64 + hi * 32 + lo) * 8);
            acck[t] = __builtin_amdgcn_mfma_f32_32x32x16_bf16(af[s], b, acck[t], 0, 0, 0);
        }
    __syncthreads();                                   // S2 (pq-dump reads done)

    // ---- phase B: pk -> C_ swz16 + pkT -> A_ swz8 ----
    #pragma unroll
    for (int t = 0; t < 2; ++t) {
        int colr = (2 * ch + t) * 32 + lo;
        #pragma unroll
        for (int g = 0; g < 4; ++g) {
            int c0 = rg * 32 + 8 * g + 4 * hi;
            bf4 pk4;
            #pragma unroll
            for (int e = 0; e < 4; ++e) {
                unsigned short bb = f2b(__expf(acck[t][4 * g + e] - sqk[4 * g + e]) * PHI_SCALE);
                pk4[e] = (short)bb;
                C_[(unsigned)(((c0 + e) * 128 + colr) ^ (((c0 + e) & 15) << 3))] = bb;
            }
            *(bf4*)&A_[(unsigned)((colr * 64 + c0) ^ ((colr & 7) << 3))] = pk4;
        }
    }
    __syncthreads();                                   // S3

    // ---- phase C: pk frag-dump; zk (MFMA); identity-MFMA vT -> regs ----
    {
        int g2 = wave & 1, sh = wave >> 1;
        #pragma unroll
        for (int s2 = 0; s2 < 4; ++s2) {
            int s = sh * 4 + s2;
            bf8 t8 = *(const bf8*)&C_[(unsigned)(((g2 * 32 + lo) * 128 + 16 * s + 8 * hi) ^ ((lo & 15) << 3))];
            *(bf8*)(pkF + (size_t)hn * 8192 + (size_t)(((g2 * 8 + s) * 64 + hi * 32 + lo) * 8)) = t8;
        }
    }
    {   // zk[r] = rowsum(pkT) via MFMA ones-column; wave handles rows wave*32..+31
        bf8 onesk;
        #pragma unroll
        for (int e = 0; e < 8; ++e) onesk[e] = (lo == 0) ? (short)0x3F80 : (short)0;
        facc16 az;
        #pragma unroll
        for (int e = 0; e < 16; ++e) az[e] = 0.f;
        #pragma unroll
        for (int s = 0; s < 4; ++s) {
            const bf8 a = *(const bf8*)&A_[(unsigned)(((wave * 32 + lo) * 64 + 16 * s + 8 * hi) ^ ((lo & 7) << 3))];
            az = __builtin_amdgcn_mfma_f32_32x32x16_bf16(a, onesk, az, 0, 0, 0);
        }
        if (lo == 0) {
            #pragma unroll
            for (int reg = 0; reg < 16; ++reg)
                zk[(size_t)hn * 128 + wave * 32 + (reg & 3) + 8 * (reg >> 2) + 4 * hi] = az[reg];
        }
    }
    bf8 aid[2];                                        // identity A-frags
    #pragma unroll
    for (int s2 = 0; s2 < 2; ++s2)
        #pragma unroll
        for (int e = 0; e < 8; ++e)
            aid[s2][e] = (e == lo - 16 * s2 - 8 * hi) ? (short)0x3F80 : (short)0;
    facc16 tv[2][2];
    #pragma unroll
    for (int t = 0; t < 2; ++t)
        #pragma unroll
        for (int u = 0; u < 2; ++u) {
            #pragma unroll
            for (int e = 0; e < 16; ++e) tv[t][u][e] = 0.f;
            #pragma unroll
            for (int s2 = 0; s2 < 2; ++s2) {
                const bf8 b = *(const bf8*)&B_[(unsigned)(((32 * u + lo) * 64 + 16 * (2 * t + s2) + 8 * hi) ^ ((lo & 7) << 3))];
                tv[t][u] = __builtin_amdgcn_mfma_f32_32x32x16_bf16(aid[s2], b, tv[t][u], 0, 0, 0);
            }
        }
    __syncthreads();                                   // S4 (pk-dump reads done)

    // ---- phase D: vT epilogue -> C_ [d][c] swz8 ----
    #pragma unroll
    for (int t = 0; t < 2; ++t)
        #pragma unroll
        for (int u = 0; u < 2; ++u)
            #pragma unroll
            for (int reg = 0; reg < 16; ++reg) {
                int d = 32 * t + (reg & 3) + 8 * (reg >> 2) + 4 * hi;
                int c = 32 * u + lo;
                C_[(unsigned)((d * 64 + c) ^ ((d & 7) << 3))] = f2b(tv[t][u][reg]);
            }
    __syncthreads();                                   // S5

    // ---- phase E: vT frag-dump; skv MFMA; skvTp dump ----
    {
        int g2 = wave & 1, sh = wave >> 1;
        #pragma unroll
        for (int s2 = 0; s2 < 2; ++s2) {
            int s = sh * 2 + s2;
            bf8 t8 = *(const bf8*)&C_[(unsigned)(((g2 * 32 + lo) * 64 + 16 * s + 8 * hi) ^ ((lo & 7) << 3))];
            *(bf8*)(vTF + (size_t)hn * 4096 + (size_t)(((g2 * 4 + s) * 64 + hi * 32 + lo) * 8)) = t8;
        }
    }
    {
        facc16 acs[2];
        #pragma unroll
        for (int t = 0; t < 2; ++t)
            #pragma unroll
            for (int e = 0; e < 16; ++e) acs[t][e] = 0.f;
        #pragma unroll
        for (int s = 0; s < 4; ++s) {
            const bf8 a = *(const bf8*)&C_[(unsigned)(((rg * 32 + lo) * 64 + 16 * s + 8 * hi) ^ ((lo & 7) << 3))];
            #pragma unroll
            for (int t = 0; t < 2; ++t) {
                const bf8 b = *(const bf8*)&A_[(unsigned)((((2 * ch + t) * 32 + lo) * 64 + 16 * s + 8 * hi) ^ ((lo & 7) << 3))];
                acs[t] = __builtin_amdgcn_mfma_f32_32x32x16_bf16(a, b, acs[t], 0, 0, 0);
            }
        }
        unsigned short* sg = skvTp + (size_t)hn * 8192;
        #pragma unroll
        for (int t = 0; t < 2; ++t)
            #pragma unroll
            for (int reg = 0; reg < 16; ++reg) {
                int d = rg * 32 + (reg & 3) + 8 * (reg >> 2) + 4 * hi;
                int r = (2 * ch + t) * 32 + lo;
                sg[d * 128 + r] = f2b(acs[t][reg]);
            }
    }
}

// ============== k2: pair-split exclusive scans (lanes 2i/2i+1 per column) ===
__global__ __launch_bounds__(256) void k2(unsigned short* __restrict__ skvTp,
                                          const float* __restrict__ zk,
                                          unsigned short* __restrict__ zkp)
{
    const int bid = blockIdx.x, tid = threadIdx.x;
    if (bid < 1024) {                                  // skv: 131072 cols x 2 halves
        int g = bid * 256 + tid;
        int cid = g >> 1, half = g & 1;
        int h = cid >> 13, dr = cid & 8191;
        unsigned short* p = skvTp + (size_t)h * NC2 * 8192 + (size_t)(half * 32) * 8192 + dr;
        unsigned short vals[32];
        #pragma unroll
        for (int n = 0; n < 32; ++n) vals[n] = p[(size_t)n * 8192];
        float T = 0.f;
        #pragma unroll
        for (int n = 0; n < 32; ++n) T += b2f(vals[n]);
        float off = __shfl_xor(T, 1);
        float run = half ? off : 0.f;
        #pragma unroll
        for (int n = 0; n < 32; ++n) {
            float t = b2f(vals[n]);
            p[(size_t)n * 8192] = f2b(run);
            run += t;
        }
    } else {                                           // zk: 2048 cols x 2 halves
        int g = (bid - 1024) * 256 + tid;
        int cid = g >> 1, half = g & 1;
        int h = cid >> 7, r = cid & 127;
        const float* pz = zk + (size_t)h * NC2 * 128 + half * 32 * 128 + r;
        unsigned short* oz = zkp + (size_t)h * NC2 * 128 + half * 32 * 128 + r;
        float vals[32];
        #pragma unroll
        for (int n = 0; n < 32; ++n) vals[n] = pz[n * 128];
        float T = 0.f;
        #pragma unroll
        for (int n = 0; n < 32; ++n) T += vals[n];
        float off = __shfl_xor(T, 1);
        float run = half ? off : 0.f;
        #pragma unroll
        for (int n = 0; n < 32; ++n) {
            oz[n * 128] = f2b(run);
            run += vals[n];
        }
    }
}

// ============== k3: GEMM1 + mask + num/den GEMM + divide (1 barrier) ========
__global__ __launch_bounds__(256) void k3(
    const unsigned short* __restrict__ pqF, const unsigned short* __restrict__ pkF,
    const unsigned short* __restrict__ vTF, const unsigned short* __restrict__ skvTp,
    const unsigned short* __restrict__ zkp, float* __restrict__ out)
{
    __shared__ __align__(16) unsigned short P_[8192];  // svl [d][r] swz16 (16KB)
    __shared__ __align__(16) unsigned short S_[4096];  // A_att [l][s] swz8 (8KB)
    const int tid = threadIdx.x, hn = blockIdx.x;
    const int lane = tid & 63, wave = tid >> 6, lo = lane & 31, hi = lane >> 5;
    const int rg = wave & 1, ch = wave >> 1;

    for (int i = tid; i < 1024; i += 256) {            // stage svl early
        bf8 t8 = *(const bf8*)(skvTp + (size_t)hn * 8192 + (size_t)i * 8);
        int d = i >> 4, r0 = (i & 15) * 8;
        *(bf8*)&P_[(unsigned)((d * 128 + r0) ^ ((d & 15) << 3))] = t8;
    }
    bf8 qf[8];
    #pragma unroll
    for (int s = 0; s < 8; ++s)
        qf[s] = *(const bf8*)(pqF + (size_t)hn * 8192 + (size_t)(((rg * 8 + s) * 64 + hi * 32 + lo) * 8));
    bf8 onesf, zf[8];
    #pragma unroll
    for (int e = 0; e < 8; ++e) onesf[e] = (lo == 0) ? (short)0x3F80 : (short)0;
    #pragma unroll
    for (int s = 0; s < 8; ++s)
        #pragma unroll
        for (int e = 0; e < 8; ++e) zf[s][e] = 0;
    if (lo == 0) {
        #pragma unroll
        for (int s = 0; s < 8; ++s)
            zf[s] = *(const bf8*)(zkp + (size_t)hn * 128 + 16 * s + 8 * hi);
    }

    facc16 ac1;                                        // GEMM1: A = pq.pk^T
    #pragma unroll
    for (int e = 0; e < 16; ++e) ac1[e] = 0.f;
    #pragma unroll
    for (int s = 0; s < 8; ++s) {
        const bf8 b = *(const bf8*)(pkF + (size_t)hn * 8192 + (size_t)(((ch * 8 + s) * 64 + hi * 32 + lo) * 8));
        ac1 = __builtin_amdgcn_mfma_f32_32x32x16_bf16(qf[s], b, ac1, 0, 0, 0);
    }
    #pragma unroll
    for (int reg = 0; reg < 16; ++reg) {               // masked A -> S_
        int row = rg * 32 + (reg & 3) + 8 * (reg >> 2) + 4 * hi;
        int sc = ch * 32 + lo;
        S_[(unsigned)((row * 64 + sc) ^ ((row & 7) << 3))] = f2b(sc < row ? ac1[reg] : 0.f);
    }
    __syncthreads();                                   // S1 (A_att + svl visible)

    facc16 an, ad;
    #pragma unroll
    for (int e = 0; e < 16; ++e) { an[e] = 0.f; ad[e] = 0.f; }
    #pragma unroll
    for (int s = 0; s < 4; ++s) {                      // pass A: k = c
        const bf8 a = *(const bf8*)&S_[(unsigned)(((rg * 32 + lo) * 64 + 16 * s + 8 * hi) ^ ((lo & 7) << 3))];
        const bf8 b = *(const bf8*)(vTF + (size_t)hn * 4096 + (size_t)(((ch * 4 + s) * 64 + hi * 32 + lo) * 8));
        an = __builtin_amdgcn_mfma_f32_32x32x16_bf16(a, b, an, 0, 0, 0);
        ad = __builtin_amdgcn_mfma_f32_32x32x16_bf16(a, onesf, ad, 0, 0, 0);
    }
    #pragma unroll
    for (int s = 0; s < 8; ++s) {                      // pass B: k = r
        const bf8 b = *(const bf8*)&P_[(unsigned)(((ch * 32 + lo) * 128 + 16 * s + 8 * hi) ^ ((lo & 15) << 3))];
        an = __builtin_amdgcn_mfma_f32_32x32x16_bf16(qf[s], b, an, 0, 0, 0);
        ad = __builtin_amdgcn_mfma_f32_32x32x16_bf16(qf[s], zf[s], ad, 0, 0, 0);
    }
    float* og = out + (size_t)hn * C2 * D;
    #pragma unroll
    for (int reg = 0; reg < 16; ++reg) {
        int row = rg * 32 + (reg & 3) + 8 * (reg >> 2) + 4 * hi;
        float dv = __shfl(ad[reg], lane & 32);
        og[row * 64 + ch * 32 + lo] = an[reg] / (dv + EPS);
    }
}

// ---------------------------------------------------------------------------
extern "C" void kernel_launch(void* const* d_in, const int* in_sizes, int n_in,
                              void* d_out, int out_size, void* d_ws, size_t ws_size,
                              hipStream_t stream) {
    // setup_inputs order: {T, k, q, v, W}
    const float* k = (const float*)d_in[1];
    const float* q = (const float*)d_in[2];
    const float* v = (const float*)d_in[3];
    const float* W = (const float*)d_in[4];
    float* out = (float*)d_out;

    // ws (u16 units): pqF 16MB | pkF 16MB | vTF 8MB | skvTp 16MB | WF | zkp | zk
    unsigned short* pqF   = (unsigned short*)d_ws;
    unsigned short* pkF   = pqF + (size_t)HN2 * 8192;
    unsigned short* vTF   = pkF + (size_t)HN2 * 8192;
    unsigned short* skvTp = vTF + (size_t)HN2 * 4096;
    unsigned short* WF    = skvTp + (size_t)HN2 * 8192;
    unsigned short* zkp   = WF + 8192;
    float* zk             = (float*)(zkp + (size_t)HN2 * 128);

    kW<<<1, 256, 0, stream>>>(W, WF);
    k1<<<HN2, 256, 0, stream>>>(q, k, v, WF, pqF, pkF, vTF, skvTp, zk);
    k2<<<1040, 256, 0, stream>>>(skvTp, zk, zkp);
    k3<<<HN2, 256, 0, stream>>>(pqF, pkF, vTF, skvTp, zkp, out);
}

// Round 13
// 60.919 us; speedup vs baseline: 1.2594x; 1.0766x over previous
//
#include <hip/hip_runtime.h>
#include <hip/hip_bf16.h>

#define H 16
#define L 4096
#define D 64
#define R 128
#define C2 64
#define NC2 64
#define HN2 (H * NC2)      // 1024 chunks
#define EPS 1e-10f
#define XS_SCALE 0.125f                    // sqrt(0.125)/64^0.25 == 1/8 exactly
#define PHI_SCALE 0.08838834764831845f     // 1/sqrt(128)

typedef __attribute__((ext_vector_type(8))) short bf8;     // 8 bf16
typedef __attribute__((ext_vector_type(4))) short bf4;     // 4 bf16
typedef __attribute__((ext_vector_type(16))) float facc16; // 32x32 MFMA acc

static __device__ __forceinline__ unsigned short f2b(float f) {
    union { __hip_bfloat16 h; unsigned short u; } c;
    c.h = __float2bfloat16(f);                 // hw v_cvt (RNE), 1 op
    return c.u;
}
static __device__ __forceinline__ float b2f(unsigned short s) {
    return __uint_as_float(((unsigned)s) << 16);
}

// ============== kW: W -> WF (bf16, MFMA-B fragment order) ===================
// WF slot ((tile*4+s)*64 + hi*32 + lo)*8 + e  =  W[d=16s+8hi+e][r=32*tile+lo]
__global__ __launch_bounds__(256) void kW(const float* __restrict__ W,
                                          unsigned short* __restrict__ WF) {
    __shared__ float wl[8192];
    for (int i = threadIdx.x; i < 8192; i += 256) wl[i] = W[i];
    __syncthreads();
    for (int i = threadIdx.x; i < 1024; i += 256) {
        int tile = i >> 8, s = (i >> 6) & 3, hi = (i >> 5) & 1, lo = i & 31;
        int r = tile * 32 + lo;
        #pragma unroll
        for (int e = 0; e < 8; ++e)
            WF[i * 8 + e] = f2b(wl[(16 * s + 8 * hi + e) * 128 + r]);
    }
}

// ============== k1: phi_q, phi_k, vT, skv, zk — frag-layout dumps (R9) ======
__global__ __launch_bounds__(256, 4) void k1(
    const float* __restrict__ q, const float* __restrict__ k,
    const float* __restrict__ v, const unsigned short* __restrict__ WF,
    unsigned short* __restrict__ pqF, unsigned short* __restrict__ pkF,
    unsigned short* __restrict__ vTF, unsigned short* __restrict__ skvTp,
    float* __restrict__ zk)
{
    __shared__ __align__(16) unsigned short A_[8192];  // pkT[r][c] swz8 (16KB)
    __shared__ __align__(16) unsigned short B_[4096];  // v linear swz8   (8KB)
    __shared__ __align__(16) unsigned short C_[8192];  // pq/pk swz16 -> vT swz8 (16KB)
    const int tid = threadIdx.x, hn = blockIdx.x;
    const int lane = tid & 63, wave = tid >> 6, lo = lane & 31, hi = lane >> 5;
    const int rg = wave & 1, ch = wave >> 1;
    const size_t cbase = (size_t)hn * C2 * D;
    const int prow = tid >> 4, pd0 = (tid & 15) * 4;

    // ---- phase 0: q A-frags direct from global + ssq (no LDS) ----
    bf8 af[4];
    float sqrow[16];
    {
        float ssq = 0.f;
        #pragma unroll
        for (int s = 0; s < 4; ++s) {
            const float* qp = q + cbase + (rg * 32 + lo) * 64 + 16 * s + 8 * hi;
            float4 f0 = *(const float4*)qp;
            float4 f1 = *(const float4*)(qp + 4);
            float x0 = f0.x * XS_SCALE, x1 = f0.y * XS_SCALE, x2 = f0.z * XS_SCALE, x3 = f0.w * XS_SCALE;
            float x4 = f1.x * XS_SCALE, x5 = f1.y * XS_SCALE, x6 = f1.z * XS_SCALE, x7 = f1.w * XS_SCALE;
            ssq += x0*x0 + x1*x1 + x2*x2 + x3*x3 + x4*x4 + x5*x5 + x6*x6 + x7*x7;
            bf8 a;
            a[0]=(short)f2b(x0); a[1]=(short)f2b(x1); a[2]=(short)f2b(x2); a[3]=(short)f2b(x3);
            a[4]=(short)f2b(x4); a[5]=(short)f2b(x5); a[6]=(short)f2b(x6); a[7]=(short)f2b(x7);
            af[s] = a;
        }
        ssq += __shfl_xor(ssq, 32); ssq *= 0.5f;
        #pragma unroll
        for (int r2 = 0; r2 < 16; ++r2)
            sqrow[r2] = __shfl(ssq, (r2 & 3) + 8 * (r2 >> 2) + 4 * hi);
    }
    {   // phi_q MFMA (B-frags from WF global) -> C_ pq[c][r] swz16
        facc16 acc[2];
        #pragma unroll
        for (int t = 0; t < 2; ++t)
            #pragma unroll
            for (int e = 0; e < 16; ++e) acc[t][e] = 0.f;
        #pragma unroll
        for (int s = 0; s < 4; ++s)
            #pragma unroll
            for (int t = 0; t < 2; ++t) {
                const bf8 b = *(const bf8*)(WF + (((2 * ch + t) * 4 + s) * 64 + hi * 32 + lo) * 8);
                acc[t] = __builtin_amdgcn_mfma_f32_32x32x16_bf16(af[s], b, acc[t], 0, 0, 0);
            }
        #pragma unroll
        for (int t = 0; t < 2; ++t)
            #pragma unroll
            for (int reg = 0; reg < 16; ++reg) {
                int row = rg * 32 + (reg & 3) + 8 * (reg >> 2) + 4 * hi;
                int col = (2 * ch + t) * 32 + lo;
                C_[(unsigned)((row * 128 + col) ^ ((row & 15) << 3))] =
                    f2b(__expf(acc[t][reg] - sqrow[reg]) * PHI_SCALE);
            }
    }
    __syncthreads();                                   // S1

    // ---- phase A: pq frag-dump; k A-frags; phi_k MFMA ----
    {
        int g2 = wave & 1, sh = wave >> 1;
        #pragma unroll
        for (int s2 = 0; s2 < 4; ++s2) {
            int s = sh * 4 + s2;
            bf8 t8 = *(const bf8*)&C_[(unsigned)(((g2 * 32 + lo) * 128 + 16 * s + 8 * hi) ^ ((lo & 15) << 3))];
            *(bf8*)(pqF + (size_t)hn * 8192 + (size_t)(((g2 * 8 + s) * 64 + hi * 32 + lo) * 8)) = t8;
        }
    }
    float sqk[16];
    {
        float ssq = 0.f;
        #pragma unroll
        for (int s = 0; s < 4; ++s) {
            const float* kp = k + cbase + (rg * 32 + lo) * 64 + 16 * s + 8 * hi;
            float4 f0 = *(const float4*)kp;
            float4 f1 = *(const float4*)(kp + 4);
            float x0 = f0.x * XS_SCALE, x1 = f0.y * XS_SCALE, x2 = f0.z * XS_SCALE, x3 = f0.w * XS_SCALE;
            float x4 = f1.x * XS_SCALE, x5 = f1.y * XS_SCALE, x6 = f1.z * XS_SCALE, x7 = f1.w * XS_SCALE;
            ssq += x0*x0 + x1*x1 + x2*x2 + x3*x3 + x4*x4 + x5*x5 + x6*x6 + x7*x7;
            bf8 a;
            a[0]=(short)f2b(x0); a[1]=(short)f2b(x1); a[2]=(short)f2b(x2); a[3]=(short)f2b(x3);
            a[4]=(short)f2b(x4); a[5]=(short)f2b(x5); a[6]=(short)f2b(x6); a[7]=(short)f2b(x7);
            af[s] = a;
        }
        ssq += __shfl_xor(ssq, 32); ssq *= 0.5f;
        #pragma unroll
        for (int r2 = 0; r2 < 16; ++r2)
            sqk[r2] = __shfl(ssq, (r2 & 3) + 8 * (r2 >> 2) + 4 * hi);
    }
    facc16 acck[2];
    #pragma unroll
    for (int t = 0; t < 2; ++t)
        #pragma unroll
        for (int e = 0; e < 16; ++e) acck[t][e] = 0.f;
    #pragma unroll
    for (int s = 0; s < 4; ++s)
        #pragma unroll
        for (int t = 0; t < 2; ++t) {
            const bf8 b = *(const bf8*)(WF + (((2 * ch + t) * 4 + s) * 64 + hi * 32 + lo) * 8);
            acck[t] = __builtin_amdgcn_mfma_f32_32x32x16_bf16(af[s], b, acck[t], 0, 0, 0);
        }
    __syncthreads();                                   // S2 (pq-dump reads done)

    // ---- phase B: pk -> C_ swz16 + pkT -> A_ swz8 ; v -> B_ ----
    #pragma unroll
    for (int t = 0; t < 2; ++t) {
        int colr = (2 * ch + t) * 32 + lo;
        #pragma unroll
        for (int g = 0; g < 4; ++g) {
            int c0 = rg * 32 + 8 * g + 4 * hi;
            bf4 pk4;
            #pragma unroll
            for (int e = 0; e < 4; ++e) {
                unsigned short bb = f2b(__expf(acck[t][4 * g + e] - sqk[4 * g + e]) * PHI_SCALE);
                pk4[e] = (short)bb;
                C_[(unsigned)(((c0 + e) * 128 + colr) ^ (((c0 + e) & 15) << 3))] = bb;
            }
            *(bf4*)&A_[(unsigned)((colr * 64 + c0) ^ ((colr & 7) << 3))] = pk4;
        }
    }
    #pragma unroll
    for (int n = 0; n < 4; ++n) {                      // v -> B_ linear swz8
        int row = prow + 16 * n;
        float4 vv = *(const float4*)(v + cbase + row * 64 + pd0);
        unsigned* p = (unsigned*)&B_[(unsigned)((row * 64 + pd0) ^ ((row & 7) << 3))];
        p[0] = (unsigned)f2b(vv.x) | ((unsigned)f2b(vv.y) << 16);
        p[1] = (unsigned)f2b(vv.z) | ((unsigned)f2b(vv.w) << 16);
    }
    __syncthreads();                                   // S3

    // ---- phase C: pk frag-dump; zk (MFMA); identity-MFMA vT -> regs ----
    {
        int g2 = wave & 1, sh = wave >> 1;
        #pragma unroll
        for (int s2 = 0; s2 < 4; ++s2) {
            int s = sh * 4 + s2;
            bf8 t8 = *(const bf8*)&C_[(unsigned)(((g2 * 32 + lo) * 128 + 16 * s + 8 * hi) ^ ((lo & 15) << 3))];
            *(bf8*)(pkF + (size_t)hn * 8192 + (size_t)(((g2 * 8 + s) * 64 + hi * 32 + lo) * 8)) = t8;
        }
    }
    {   // zk[r] = rowsum(pkT) via MFMA ones-column; wave handles rows wave*32..+31
        bf8 onesk;
        #pragma unroll
        for (int e = 0; e < 8; ++e) onesk[e] = (lo == 0) ? (short)0x3F80 : (short)0;
        facc16 az;
        #pragma unroll
        for (int e = 0; e < 16; ++e) az[e] = 0.f;
        #pragma unroll
        for (int s = 0; s < 4; ++s) {
            const bf8 a = *(const bf8*)&A_[(unsigned)(((wave * 32 + lo) * 64 + 16 * s + 8 * hi) ^ ((lo & 7) << 3))];
            az = __builtin_amdgcn_mfma_f32_32x32x16_bf16(a, onesk, az, 0, 0, 0);
        }
        if (lo == 0) {
            #pragma unroll
            for (int reg = 0; reg < 16; ++reg)
                zk[(size_t)hn * 128 + wave * 32 + (reg & 3) + 8 * (reg >> 2) + 4 * hi] = az[reg];
        }
    }
    bf8 aid[2];                                        // identity A-frags
    #pragma unroll
    for (int s2 = 0; s2 < 2; ++s2)
        #pragma unroll
        for (int e = 0; e < 8; ++e)
            aid[s2][e] = (e == lo - 16 * s2 - 8 * hi) ? (short)0x3F80 : (short)0;
    facc16 tv[2][2];
    #pragma unroll
    for (int t = 0; t < 2; ++t)
        #pragma unroll
        for (int u = 0; u < 2; ++u) {
            #pragma unroll
            for (int e = 0; e < 16; ++e) tv[t][u][e] = 0.f;
            #pragma unroll
            for (int s2 = 0; s2 < 2; ++s2) {
                const bf8 b = *(const bf8*)&B_[(unsigned)(((32 * u + lo) * 64 + 16 * (2 * t + s2) + 8 * hi) ^ ((lo & 7) << 3))];
                tv[t][u] = __builtin_amdgcn_mfma_f32_32x32x16_bf16(aid[s2], b, tv[t][u], 0, 0, 0);
            }
        }
    __syncthreads();                                   // S4 (pk-dump reads done)

    // ---- phase D: vT epilogue -> C_ [d][c] swz8 ----
    #pragma unroll
    for (int t = 0; t < 2; ++t)
        #pragma unroll
        for (int u = 0; u < 2; ++u)
            #pragma unroll
            for (int reg = 0; reg < 16; ++reg) {
                int d = 32 * t + (reg & 3) + 8 * (reg >> 2) + 4 * hi;
                int c = 32 * u + lo;
                C_[(unsigned)((d * 64 + c) ^ ((d & 7) << 3))] = f2b(tv[t][u][reg]);
            }
    __syncthreads();                                   // S5

    // ---- phase E: vT frag-dump; skv MFMA; skvTp dump ----
    {
        int g2 = wave & 1, sh = wave >> 1;
        #pragma unroll
        for (int s2 = 0; s2 < 2; ++s2) {
            int s = sh * 2 + s2;
            bf8 t8 = *(const bf8*)&C_[(unsigned)(((g2 * 32 + lo) * 64 + 16 * s + 8 * hi) ^ ((lo & 7) << 3))];
            *(bf8*)(vTF + (size_t)hn * 4096 + (size_t)(((g2 * 4 + s) * 64 + hi * 32 + lo) * 8)) = t8;
        }
    }
    {
        facc16 acs[2];
        #pragma unroll
        for (int t = 0; t < 2; ++t)
            #pragma unroll
            for (int e = 0; e < 16; ++e) acs[t][e] = 0.f;
        #pragma unroll
        for (int s = 0; s < 4; ++s) {
            const bf8 a = *(const bf8*)&C_[(unsigned)(((rg * 32 + lo) * 64 + 16 * s + 8 * hi) ^ ((lo & 7) << 3))];
            #pragma unroll
            for (int t = 0; t < 2; ++t) {
                const bf8 b = *(const bf8*)&A_[(unsigned)((((2 * ch + t) * 32 + lo) * 64 + 16 * s + 8 * hi) ^ ((lo & 7) << 3))];
                acs[t] = __builtin_amdgcn_mfma_f32_32x32x16_bf16(a, b, acs[t], 0, 0, 0);
            }
        }
        unsigned short* sg = skvTp + (size_t)hn * 8192;
        #pragma unroll
        for (int t = 0; t < 2; ++t)
            #pragma unroll
            for (int reg = 0; reg < 16; ++reg) {
                int d = rg * 32 + (reg & 3) + 8 * (reg >> 2) + 4 * hi;
                int r = (2 * ch + t) * 32 + lo;
                sg[d * 128 + r] = f2b(acs[t][reg]);
            }
    }
}

// ============== k2: pair-split exclusive scans (lanes 2i/2i+1 per column) ===
__global__ __launch_bounds__(256) void k2(unsigned short* __restrict__ skvTp,
                                          const float* __restrict__ zk,
                                          unsigned short* __restrict__ zkp)
{
    const int bid = blockIdx.x, tid = threadIdx.x;
    if (bid < 1024) {                                  // skv: 131072 cols x 2 halves
        int g = bid * 256 + tid;
        int cid = g >> 1, half = g & 1;
        int h = cid >> 13, dr = cid & 8191;
        unsigned short* p = skvTp + (size_t)h * NC2 * 8192 + (size_t)(half * 32) * 8192 + dr;
        unsigned short vals[32];
        #pragma unroll
        for (int n = 0; n < 32; ++n) vals[n] = p[(size_t)n * 8192];
        float T = 0.f;
        #pragma unroll
        for (int n = 0; n < 32; ++n) T += b2f(vals[n]);
        float off = __shfl_xor(T, 1);
        float run = half ? off : 0.f;
        #pragma unroll
        for (int n = 0; n < 32; ++n) {
            float t = b2f(vals[n]);
            p[(size_t)n * 8192] = f2b(run);
            run += t;
        }
    } else {                                           // zk: 2048 cols x 2 halves
        int g = (bid - 1024) * 256 + tid;
        int cid = g >> 1, half = g & 1;
        int h = cid >> 7, r = cid & 127;
        const float* pz = zk + (size_t)h * NC2 * 128 + half * 32 * 128 + r;
        unsigned short* oz = zkp + (size_t)h * NC2 * 128 + half * 32 * 128 + r;
        float vals[32];
        #pragma unroll
        for (int n = 0; n < 32; ++n) vals[n] = pz[n * 128];
        float T = 0.f;
        #pragma unroll
        for (int n = 0; n < 32; ++n) T += vals[n];
        float off = __shfl_xor(T, 1);
        float run = half ? off : 0.f;
        #pragma unroll
        for (int n = 0; n < 32; ++n) {
            oz[n * 128] = f2b(run);
            run += vals[n];
        }
    }
}

// ============== k3: GEMM1 + mask + num/den GEMM + divide (1 barrier) ========
__global__ __launch_bounds__(256) void k3(
    const unsigned short* __restrict__ pqF, const unsigned short* __restrict__ pkF,
    const unsigned short* __restrict__ vTF, const unsigned short* __restrict__ skvTp,
    const unsigned short* __restrict__ zkp, float* __restrict__ out)
{
    __shared__ __align__(16) unsigned short P_[8192];  // svl [d][r] swz16 (16KB)
    __shared__ __align__(16) unsigned short S_[4096];  // A_att [l][s] swz8 (8KB)
    const int tid = threadIdx.x, hn = blockIdx.x;
    const int lane = tid & 63, wave = tid >> 6, lo = lane & 31, hi = lane >> 5;
    const int rg = wave & 1, ch = wave >> 1;

    for (int i = tid; i < 1024; i += 256) {            // stage svl early
        bf8 t8 = *(const bf8*)(skvTp + (size_t)hn * 8192 + (size_t)i * 8);
        int d = i >> 4, r0 = (i & 15) * 8;
        *(bf8*)&P_[(unsigned)((d * 128 + r0) ^ ((d & 15) << 3))] = t8;
    }
    bf8 qf[8];
    #pragma unroll
    for (int s = 0; s < 8; ++s)
        qf[s] = *(const bf8*)(pqF + (size_t)hn * 8192 + (size_t)(((rg * 8 + s) * 64 + hi * 32 + lo) * 8));
    bf8 onesf, zf[8];
    #pragma unroll
    for (int e = 0; e < 8; ++e) onesf[e] = (lo == 0) ? (short)0x3F80 : (short)0;
    #pragma unroll
    for (int s = 0; s < 8; ++s)
        #pragma unroll
        for (int e = 0; e < 8; ++e) zf[s][e] = 0;
    if (lo == 0) {
        #pragma unroll
        for (int s = 0; s < 8; ++s)
            zf[s] = *(const bf8*)(zkp + (size_t)hn * 128 + 16 * s + 8 * hi);
    }

    facc16 ac1;                                        // GEMM1: A = pq.pk^T
    #pragma unroll
    for (int e = 0; e < 16; ++e) ac1[e] = 0.f;
    #pragma unroll
    for (int s = 0; s < 8; ++s) {
        const bf8 b = *(const bf8*)(pkF + (size_t)hn * 8192 + (size_t)(((ch * 8 + s) * 64 + hi * 32 + lo) * 8));
        ac1 = __builtin_amdgcn_mfma_f32_32x32x16_bf16(qf[s], b, ac1, 0, 0, 0);
    }
    #pragma unroll
    for (int reg = 0; reg < 16; ++reg) {               // masked A -> S_
        int row = rg * 32 + (reg & 3) + 8 * (reg >> 2) + 4 * hi;
        int sc = ch * 32 + lo;
        S_[(unsigned)((row * 64 + sc) ^ ((row & 7) << 3))] = f2b(sc < row ? ac1[reg] : 0.f);
    }
    __syncthreads();                                   // S1 (A_att + svl visible)

    facc16 an, ad;
    #pragma unroll
    for (int e = 0; e < 16; ++e) { an[e] = 0.f; ad[e] = 0.f; }
    #pragma unroll
    for (int s = 0; s < 4; ++s) {                      // pass A: k = c
        const bf8 a = *(const bf8*)&S_[(unsigned)(((rg * 32 + lo) * 64 + 16 * s + 8 * hi) ^ ((lo & 7) << 3))];
        const bf8 b = *(const bf8*)(vTF + (size_t)hn * 4096 + (size_t)(((ch * 4 + s) * 64 + hi * 32 + lo) * 8));
        an = __builtin_amdgcn_mfma_f32_32x32x16_bf16(a, b, an, 0, 0, 0);
        ad = __builtin_amdgcn_mfma_f32_32x32x16_bf16(a, onesf, ad, 0, 0, 0);
    }
    #pragma unroll
    for (int s = 0; s < 8; ++s) {                      // pass B: k = r
        const bf8 b = *(const bf8*)&P_[(unsigned)(((ch * 32 + lo) * 128 + 16 * s + 8 * hi) ^ ((lo & 15) << 3))];
        an = __builtin_amdgcn_mfma_f32_32x32x16_bf16(qf[s], b, an, 0, 0, 0);
        ad = __builtin_amdgcn_mfma_f32_32x32x16_bf16(qf[s], zf[s], ad, 0, 0, 0);
    }
    float* og = out + (size_t)hn * C2 * D;
    #pragma unroll
    for (int reg = 0; reg < 16; ++reg) {
        int row = rg * 32 + (reg & 3) + 8 * (reg >> 2) + 4 * hi;
        float dv = __shfl(ad[reg], lane & 32);
        og[row * 64 + ch * 32 + lo] = an[reg] / (dv + EPS);
    }
}

// ---------------------------------------------------------------------------
extern "C" void kernel_launch(void* const* d_in, const int* in_sizes, int n_in,
                              void* d_out, int out_size, void* d_ws, size_t ws_size,
                              hipStream_t stream) {
    // setup_inputs order: {T, k, q, v, W}
    const float* k = (const float*)d_in[1];
    const float* q = (const float*)d_in[2];
    const float* v = (const float*)d_in[3];
    const float* W = (const float*)d_in[4];
    float* out = (float*)d_out;

    // ws (u16 units): pqF 16MB | pkF 16MB | vTF 8MB | skvTp 16MB | WF | zkp | zk
    unsigned short* pqF   = (unsigned short*)d_ws;
    unsigned short* pkF   = pqF + (size_t)HN2 * 8192;
    unsigned short* vTF   = pkF + (size_t)HN2 * 8192;
    unsigned short* skvTp = vTF + (size_t)HN2 * 4096;
    unsigned short* WF    = skvTp + (size_t)HN2 * 8192;
    unsigned short* zkp   = WF + 8192;
    float* zk             = (float*)(zkp + (size_t)HN2 * 128);

    kW<<<1, 256, 0, stream>>>(W, WF);
    k1<<<HN2, 256, 0, stream>>>(q, k, v, WF, pqF, pkF, vTF, skvTp, zk);
    k2<<<1040, 256, 0, stream>>>(skvTp, zk, zkp);
    k3<<<HN2, 256, 0, stream>>>(pqF, pkF, vTF, skvTp, zkp, out);
}

// Round 14
// 59.230 us; speedup vs baseline: 1.2953x; 1.0285x over previous
//
#include <hip/hip_runtime.h>
#include <hip/hip_bf16.h>

#define H 16
#define L 4096
#define D 64
#define R 128
#define C2 64
#define NC2 64
#define HN2 (H * NC2)      // 1024 chunks
#define EPS 1e-10f
#define XS_SCALE 0.125f                    // sqrt(0.125)/64^0.25 == 1/8 exactly
#define PHI_SCALE 0.08838834764831845f     // 1/sqrt(128)

typedef __attribute__((ext_vector_type(8))) short bf8;     // 8 bf16
typedef __attribute__((ext_vector_type(4))) short bf4;     // 4 bf16
typedef __attribute__((ext_vector_type(16))) float facc16; // 32x32 MFMA acc

static __device__ __forceinline__ unsigned short f2b(float f) {
    union { __hip_bfloat16 h; unsigned short u; } c;
    c.h = __float2bfloat16(f);                 // hw v_cvt (RNE), 1 op
    return c.u;
}
static __device__ __forceinline__ float b2f(unsigned short s) {
    return __uint_as_float(((unsigned)s) << 16);
}

// ============== kW: W -> WF (bf16, MFMA-B fragment order) ===================
// WF slot ((tile*4+s)*64 + hi*32 + lo)*8 + e  =  W[d=16s+8hi+e][r=32*tile+lo]
__global__ __launch_bounds__(256) void kW(const float* __restrict__ W,
                                          unsigned short* __restrict__ WF) {
    __shared__ float wl[8192];
    for (int i = threadIdx.x; i < 8192; i += 256) wl[i] = W[i];
    __syncthreads();
    for (int i = threadIdx.x; i < 1024; i += 256) {
        int tile = i >> 8, s = (i >> 6) & 3, hi = (i >> 5) & 1, lo = i & 31;
        int r = tile * 32 + lo;
        #pragma unroll
        for (int e = 0; e < 8; ++e)
            WF[i * 8 + e] = f2b(wl[(16 * s + 8 * hi + e) * 128 + r]);
    }
}

// ============== k1: phi_q, phi_k, GEMM1+mask, vT, skv, zk ===================
// Dumps: pqF frag-order, AF (masked A, swz8-baked), vTF frag-order,
// skvTp [d][r] bf16 chunk sums, zk f32.
__global__ __launch_bounds__(256, 4) void k1(
    const float* __restrict__ q, const float* __restrict__ k,
    const float* __restrict__ v, const unsigned short* __restrict__ WF,
    unsigned short* __restrict__ pqF, unsigned short* __restrict__ AF,
    unsigned short* __restrict__ vTF, unsigned short* __restrict__ skvTp,
    float* __restrict__ zk)
{
    __shared__ __align__(16) unsigned short A_[8192];  // pkT[r][c] swz8 (16KB)
    __shared__ __align__(16) unsigned short B_[4096];  // v linear swz8   (8KB)
    __shared__ __align__(16) unsigned short C_[8192];  // pq/pk swz16 -> A_att+vT swz8 (16KB)
    const int tid = threadIdx.x, hn = blockIdx.x;
    const int lane = tid & 63, wave = tid >> 6, lo = lane & 31, hi = lane >> 5;
    const int rg = wave & 1, ch = wave >> 1;           // each in [0,2)
    const size_t cbase = (size_t)hn * C2 * D;
    const int prow = tid >> 4, pd0 = (tid & 15) * 4;

    // ---- phase 0: q A-frags direct from global + ssq ; phi_q -> C_ ----
    bf8 af[4];
    float sqrow[16];
    {
        float ssq = 0.f;
        #pragma unroll
        for (int s = 0; s < 4; ++s) {
            const float* qp = q + cbase + (rg * 32 + lo) * 64 + 16 * s + 8 * hi;
            float4 f0 = *(const float4*)qp;
            float4 f1 = *(const float4*)(qp + 4);
            float x0 = f0.x * XS_SCALE, x1 = f0.y * XS_SCALE, x2 = f0.z * XS_SCALE, x3 = f0.w * XS_SCALE;
            float x4 = f1.x * XS_SCALE, x5 = f1.y * XS_SCALE, x6 = f1.z * XS_SCALE, x7 = f1.w * XS_SCALE;
            ssq += x0*x0 + x1*x1 + x2*x2 + x3*x3 + x4*x4 + x5*x5 + x6*x6 + x7*x7;
            bf8 a;
            a[0]=(short)f2b(x0); a[1]=(short)f2b(x1); a[2]=(short)f2b(x2); a[3]=(short)f2b(x3);
            a[4]=(short)f2b(x4); a[5]=(short)f2b(x5); a[6]=(short)f2b(x6); a[7]=(short)f2b(x7);
            af[s] = a;
        }
        ssq += __shfl_xor(ssq, 32); ssq *= 0.5f;
        #pragma unroll
        for (int r2 = 0; r2 < 16; ++r2)
            sqrow[r2] = __shfl(ssq, (r2 & 3) + 8 * (r2 >> 2) + 4 * hi);
    }
    {   // phi_q MFMA (B-frags from WF global) -> C_ pq[c][r] swz16
        facc16 acc[2];
        #pragma unroll
        for (int t = 0; t < 2; ++t)
            #pragma unroll
            for (int e = 0; e < 16; ++e) acc[t][e] = 0.f;
        #pragma unroll
        for (int s = 0; s < 4; ++s)
            #pragma unroll
            for (int t = 0; t < 2; ++t) {
                const bf8 b = *(const bf8*)(WF + (((2 * ch + t) * 4 + s) * 64 + hi * 32 + lo) * 8);
                acc[t] = __builtin_amdgcn_mfma_f32_32x32x16_bf16(af[s], b, acc[t], 0, 0, 0);
            }
        #pragma unroll
        for (int t = 0; t < 2; ++t)
            #pragma unroll
            for (int reg = 0; reg < 16; ++reg) {
                int row = rg * 32 + (reg & 3) + 8 * (reg >> 2) + 4 * hi;
                int col = (2 * ch + t) * 32 + lo;
                C_[(unsigned)((row * 128 + col) ^ ((row & 15) << 3))] =
                    f2b(__expf(acc[t][reg] - sqrow[reg]) * PHI_SCALE);
            }
    }
    __syncthreads();                                   // S1

    // ---- phase A: pq frag-dump; qf <- C_; k A-frags; phi_k MFMA ----
    {
        int g2 = wave & 1, sh = wave >> 1;
        #pragma unroll
        for (int s2 = 0; s2 < 4; ++s2) {
            int s = sh * 4 + s2;
            bf8 t8 = *(const bf8*)&C_[(unsigned)(((g2 * 32 + lo) * 128 + 16 * s + 8 * hi) ^ ((lo & 15) << 3))];
            *(bf8*)(pqF + (size_t)hn * 8192 + (size_t)(((g2 * 8 + s) * 64 + hi * 32 + lo) * 8)) = t8;
        }
    }
    bf8 qf[8];                                         // pq A-frags, live to phase C
    #pragma unroll
    for (int s = 0; s < 8; ++s)
        qf[s] = *(const bf8*)&C_[(unsigned)(((rg * 32 + lo) * 128 + 16 * s + 8 * hi) ^ ((lo & 15) << 3))];
    float sqk[16];
    {
        float ssq = 0.f;
        #pragma unroll
        for (int s = 0; s < 4; ++s) {
            const float* kp = k + cbase + (rg * 32 + lo) * 64 + 16 * s + 8 * hi;
            float4 f0 = *(const float4*)kp;
            float4 f1 = *(const float4*)(kp + 4);
            float x0 = f0.x * XS_SCALE, x1 = f0.y * XS_SCALE, x2 = f0.z * XS_SCALE, x3 = f0.w * XS_SCALE;
            float x4 = f1.x * XS_SCALE, x5 = f1.y * XS_SCALE, x6 = f1.z * XS_SCALE, x7 = f1.w * XS_SCALE;
            ssq += x0*x0 + x1*x1 + x2*x2 + x3*x3 + x4*x4 + x5*x5 + x6*x6 + x7*x7;
            bf8 a;
            a[0]=(short)f2b(x0); a[1]=(short)f2b(x1); a[2]=(short)f2b(x2); a[3]=(short)f2b(x3);
            a[4]=(short)f2b(x4); a[5]=(short)f2b(x5); a[6]=(short)f2b(x6); a[7]=(short)f2b(x7);
            af[s] = a;
        }
        ssq += __shfl_xor(ssq, 32); ssq *= 0.5f;
        #pragma unroll
        for (int r2 = 0; r2 < 16; ++r2)
            sqk[r2] = __shfl(ssq, (r2 & 3) + 8 * (r2 >> 2) + 4 * hi);
    }
    facc16 acck[2];
    #pragma unroll
    for (int t = 0; t < 2; ++t)
        #pragma unroll
        for (int e = 0; e < 16; ++e) acck[t][e] = 0.f;
    #pragma unroll
    for (int s = 0; s < 4; ++s)
        #pragma unroll
        for (int t = 0; t < 2; ++t) {
            const bf8 b = *(const bf8*)(WF + (((2 * ch + t) * 4 + s) * 64 + hi * 32 + lo) * 8);
            acck[t] = __builtin_amdgcn_mfma_f32_32x32x16_bf16(af[s], b, acck[t], 0, 0, 0);
        }
    __syncthreads();                                   // S2 (pq reads done)

    // ---- phase B: pk -> C_ swz16 + pkT -> A_ swz8 ; v -> B_ ----
    #pragma unroll
    for (int t = 0; t < 2; ++t) {
        int colr = (2 * ch + t) * 32 + lo;
        #pragma unroll
        for (int g = 0; g < 4; ++g) {
            int c0 = rg * 32 + 8 * g + 4 * hi;
            bf4 pk4;
            #pragma unroll
            for (int e = 0; e < 4; ++e) {
                unsigned short bb = f2b(__expf(acck[t][4 * g + e] - sqk[4 * g + e]) * PHI_SCALE);
                pk4[e] = (short)bb;
                C_[(unsigned)(((c0 + e) * 128 + colr) ^ (((c0 + e) & 15) << 3))] = bb;
            }
            *(bf4*)&A_[(unsigned)((colr * 64 + c0) ^ ((colr & 7) << 3))] = pk4;
        }
    }
    #pragma unroll
    for (int n = 0; n < 4; ++n) {                      // v -> B_ linear swz8
        int row = prow + 16 * n;
        float4 vv = *(const float4*)(v + cbase + row * 64 + pd0);
        unsigned* p = (unsigned*)&B_[(unsigned)((row * 64 + pd0) ^ ((row & 7) << 3))];
        p[0] = (unsigned)f2b(vv.x) | ((unsigned)f2b(vv.y) << 16);
        p[1] = (unsigned)f2b(vv.z) | ((unsigned)f2b(vv.w) << 16);
    }
    __syncthreads();                                   // S3

    // ---- phase C: GEMM1 (qf x pk); zk MFMA; vT identity-MFMA (1 tile/wave) --
    facc16 ac1;                                        // A_att quadrant (rg,ch)
    #pragma unroll
    for (int e = 0; e < 16; ++e) ac1[e] = 0.f;
    #pragma unroll
    for (int s = 0; s < 8; ++s) {
        const bf8 b = *(const bf8*)&C_[(unsigned)(((ch * 32 + lo) * 128 + 16 * s + 8 * hi) ^ ((lo & 15) << 3))];
        ac1 = __builtin_amdgcn_mfma_f32_32x32x16_bf16(qf[s], b, ac1, 0, 0, 0);
    }
    {   // zk[r] = rowsum(pkT) via MFMA ones-column; wave handles rows wave*32..+31
        bf8 onesk;
        #pragma unroll
        for (int e = 0; e < 8; ++e) onesk[e] = (lo == 0) ? (short)0x3F80 : (short)0;
        facc16 az;
        #pragma unroll
        for (int e = 0; e < 16; ++e) az[e] = 0.f;
        #pragma unroll
        for (int s = 0; s < 4; ++s) {
            const bf8 a = *(const bf8*)&A_[(unsigned)(((wave * 32 + lo) * 64 + 16 * s + 8 * hi) ^ ((lo & 7) << 3))];
            az = __builtin_amdgcn_mfma_f32_32x32x16_bf16(a, onesk, az, 0, 0, 0);
        }
        if (lo == 0) {
            #pragma unroll
            for (int reg = 0; reg < 16; ++reg)
                zk[(size_t)hn * 128 + wave * 32 + (reg & 3) + 8 * (reg >> 2) + 4 * hi] = az[reg];
        }
    }
    facc16 tv;                                         // vT tile: d-tile=ch, c-tile=rg
    {
        bf8 aid[2];
        #pragma unroll
        for (int s2 = 0; s2 < 2; ++s2)
            #pragma unroll
            for (int e = 0; e < 8; ++e)
                aid[s2][e] = (e == lo - 16 * s2 - 8 * hi) ? (short)0x3F80 : (short)0;
        #pragma unroll
        for (int e = 0; e < 16; ++e) tv[e] = 0.f;
        #pragma unroll
        for (int s2 = 0; s2 < 2; ++s2) {
            const bf8 b = *(const bf8*)&B_[(unsigned)(((32 * rg + lo) * 64 + 16 * (2 * ch + s2) + 8 * hi) ^ ((lo & 7) << 3))];
            tv = __builtin_amdgcn_mfma_f32_32x32x16_bf16(aid[s2], b, tv, 0, 0, 0);
        }
    }
    __syncthreads();                                   // S4 (C_ pk reads done)

    // ---- phase D: masked A_att -> C_[0:4096] swz8 ; vT tile -> C_[4096+] ----
    #pragma unroll
    for (int reg = 0; reg < 16; ++reg) {
        int row = rg * 32 + (reg & 3) + 8 * (reg >> 2) + 4 * hi;
        int sc = ch * 32 + lo;
        C_[(unsigned)((row * 64 + sc) ^ ((row & 7) << 3))] = f2b(sc < row ? ac1[reg] : 0.f);
    }
    #pragma unroll
    for (int reg = 0; reg < 16; ++reg) {
        int d = ch * 32 + (reg & 3) + 8 * (reg >> 2) + 4 * hi;
        int c = rg * 32 + lo;
        C_[4096 + (unsigned)((d * 64 + c) ^ ((d & 7) << 3))] = f2b(tv[reg]);
    }
    __syncthreads();                                   // S5

    // ---- phase E: AF dump; vTF frag-dump; skv MFMA; skvTp dump ----
    for (int i = tid; i < 512; i += 256)               // AF (swz8 baked) linear
        *(bf8*)(AF + (size_t)hn * 4096 + (size_t)i * 8) = *(const bf8*)&C_[i * 8];
    {
        int g2 = wave & 1, sh = wave >> 1;
        #pragma unroll
        for (int s2 = 0; s2 < 2; ++s2) {
            int s = sh * 2 + s2;
            bf8 t8 = *(const bf8*)&C_[4096 + (unsigned)(((g2 * 32 + lo) * 64 + 16 * s + 8 * hi) ^ ((lo & 7) << 3))];
            *(bf8*)(vTF + (size_t)hn * 4096 + (size_t)(((g2 * 4 + s) * 64 + hi * 32 + lo) * 8)) = t8;
        }
    }
    {
        facc16 acs[2];
        #pragma unroll
        for (int t = 0; t < 2; ++t)
            #pragma unroll
            for (int e = 0; e < 16; ++e) acs[t][e] = 0.f;
        #pragma unroll
        for (int s = 0; s < 4; ++s) {
            const bf8 a = *(const bf8*)&C_[4096 + (unsigned)(((rg * 32 + lo) * 64 + 16 * s + 8 * hi) ^ ((lo & 7) << 3))];
            #pragma unroll
            for (int t = 0; t < 2; ++t) {
                const bf8 b = *(const bf8*)&A_[(unsigned)((((2 * ch + t) * 32 + lo) * 64 + 16 * s + 8 * hi) ^ ((lo & 7) << 3))];
                acs[t] = __builtin_amdgcn_mfma_f32_32x32x16_bf16(a, b, acs[t], 0, 0, 0);
            }
        }
        unsigned short* sg = skvTp + (size_t)hn * 8192;
        #pragma unroll
        for (int t = 0; t < 2; ++t)
            #pragma unroll
            for (int reg = 0; reg < 16; ++reg) {
                int d = rg * 32 + (reg & 3) + 8 * (reg >> 2) + 4 * hi;
                int r = (2 * ch + t) * 32 + lo;
                sg[d * 128 + r] = f2b(acs[t][reg]);
            }
    }
}

// ============== k2: exclusive prefix over chunks (R9 form, coalesced) =======
__global__ __launch_bounds__(256) void k2(unsigned short* __restrict__ skvTp,
                                          const float* __restrict__ zk,
                                          unsigned short* __restrict__ zkp)
{
    const int bid = blockIdx.x, tid = threadIdx.x;
    if (bid < 512) {
        int g = bid * 256 + tid;                       // H*D*R = 131072 cols
        int h = g >> 13, dr = g & 8191;
        unsigned short* p = skvTp + (size_t)h * NC2 * 8192 + dr;
        unsigned short vals[NC2];
        #pragma unroll
        for (int n = 0; n < NC2; ++n) vals[n] = p[(size_t)n * 8192];
        float run = 0.f;
        #pragma unroll
        for (int n = 0; n < NC2; ++n) {
            float t = b2f(vals[n]);
            p[(size_t)n * 8192] = f2b(run);
            run += t;
        }
    } else {
        int g2 = (bid - 512) * 256 + tid;              // H*R = 2048 cols
        int h = g2 >> 7, r = g2 & 127;
        const float* pz = zk + (size_t)h * NC2 * 128 + r;
        unsigned short* oz = zkp + (size_t)h * NC2 * 128 + r;
        float vals[NC2];
        #pragma unroll
        for (int n = 0; n < NC2; ++n) vals[n] = pz[n * 128];
        float run = 0.f;
        #pragma unroll
        for (int n = 0; n < NC2; ++n) {
            oz[n * 128] = f2b(run);
            run += vals[n];
        }
    }
}

// ============== k3: num/den GEMM + divide (no GEMM1, 1 barrier) =============
__global__ __launch_bounds__(256) void k3(
    const unsigned short* __restrict__ pqF, const unsigned short* __restrict__ AF,
    const unsigned short* __restrict__ vTF, const unsigned short* __restrict__ skvTp,
    const unsigned short* __restrict__ zkp, float* __restrict__ out)
{
    __shared__ __align__(16) unsigned short P_[8192];  // svl [d][r] swz16 (16KB)
    __shared__ __align__(16) unsigned short S_[4096];  // A_att [l][s] swz8 (8KB)
    const int tid = threadIdx.x, hn = blockIdx.x;
    const int lane = tid & 63, wave = tid >> 6, lo = lane & 31, hi = lane >> 5;
    const int rg = wave & 1, ch = wave >> 1;

    for (int i = tid; i < 512; i += 256)               // S_ <- AF (swz8 baked)
        *(bf8*)&S_[i * 8] = *(const bf8*)(AF + (size_t)hn * 4096 + (size_t)i * 8);
    for (int i = tid; i < 1024; i += 256) {            // stage svl
        bf8 t8 = *(const bf8*)(skvTp + (size_t)hn * 8192 + (size_t)i * 8);
        int d = i >> 4, r0 = (i & 15) * 8;
        *(bf8*)&P_[(unsigned)((d * 128 + r0) ^ ((d & 15) << 3))] = t8;
    }
    bf8 qf[8];
    #pragma unroll
    for (int s = 0; s < 8; ++s)
        qf[s] = *(const bf8*)(pqF + (size_t)hn * 8192 + (size_t)(((rg * 8 + s) * 64 + hi * 32 + lo) * 8));
    bf8 onesf, zf[8];
    #pragma unroll
    for (int e = 0; e < 8; ++e) onesf[e] = (lo == 0) ? (short)0x3F80 : (short)0;
    #pragma unroll
    for (int s = 0; s < 8; ++s)
        #pragma unroll
        for (int e = 0; e < 8; ++e) zf[s][e] = 0;
    if (lo == 0) {
        #pragma unroll
        for (int s = 0; s < 8; ++s)
            zf[s] = *(const bf8*)(zkp + (size_t)hn * 128 + 16 * s + 8 * hi);
    }
    __syncthreads();                                   // S1 (S_ + P_ visible)

    facc16 an, ad;
    #pragma unroll
    for (int e = 0; e < 16; ++e) { an[e] = 0.f; ad[e] = 0.f; }
    #pragma unroll
    for (int s = 0; s < 4; ++s) {                      // pass A: k = c
        const bf8 a = *(const bf8*)&S_[(unsigned)(((rg * 32 + lo) * 64 + 16 * s + 8 * hi) ^ ((lo & 7) << 3))];
        const bf8 b = *(const bf8*)(vTF + (size_t)hn * 4096 + (size_t)(((ch * 4 + s) * 64 + hi * 32 + lo) * 8));
        an = __builtin_amdgcn_mfma_f32_32x32x16_bf16(a, b, an, 0, 0, 0);
        ad = __builtin_amdgcn_mfma_f32_32x32x16_bf16(a, onesf, ad, 0, 0, 0);
    }
    #pragma unroll
    for (int s = 0; s < 8; ++s) {                      // pass B: k = r
        const bf8 b = *(const bf8*)&P_[(unsigned)(((ch * 32 + lo) * 128 + 16 * s + 8 * hi) ^ ((lo & 15) << 3))];
        an = __builtin_amdgcn_mfma_f32_32x32x16_bf16(qf[s], b, an, 0, 0, 0);
        ad = __builtin_amdgcn_mfma_f32_32x32x16_bf16(qf[s], zf[s], ad, 0, 0, 0);
    }
    float* og = out + (size_t)hn * C2 * D;
    #pragma unroll
    for (int reg = 0; reg < 16; ++reg) {
        int row = rg * 32 + (reg & 3) + 8 * (reg >> 2) + 4 * hi;
        float dv = __shfl(ad[reg], lane & 32);
        og[row * 64 + ch * 32 + lo] = an[reg] / (dv + EPS);
    }
}

// ---------------------------------------------------------------------------
extern "C" void kernel_launch(void* const* d_in, const int* in_sizes, int n_in,
                              void* d_out, int out_size, void* d_ws, size_t ws_size,
                              hipStream_t stream) {
    // setup_inputs order: {T, k, q, v, W}
    const float* k = (const float*)d_in[1];
    const float* q = (const float*)d_in[2];
    const float* v = (const float*)d_in[3];
    const float* W = (const float*)d_in[4];
    float* out = (float*)d_out;

    // ws (u16): pqF 16MB | AF 8MB | vTF 8MB | skvTp 16MB | WF | zkp | zk
    unsigned short* pqF   = (unsigned short*)d_ws;
    unsigned short* AF    = pqF + (size_t)HN2 * 8192;
    unsigned short* vTF   = AF + (size_t)HN2 * 4096;
    unsigned short* skvTp = vTF + (size_t)HN2 * 4096;
    unsigned short* WF    = skvTp + (size_t)HN2 * 8192;
    unsigned short* zkp   = WF + 8192;
    float* zk             = (float*)(zkp + (size_t)HN2 * 128);

    kW<<<1, 256, 0, stream>>>(W, WF);
    k1<<<HN2, 256, 0, stream>>>(q, k, v, WF, pqF, AF, vTF, skvTp, zk);
    k2<<<520, 256, 0, stream>>>(skvTp, zk, zkp);
    k3<<<HN2, 256, 0, stream>>>(pqF, AF, vTF, skvTp, zkp, out);
}

// Round 15
// 54.303 us; speedup vs baseline: 1.4128x; 1.0907x over previous
//
#include <hip/hip_runtime.h>
#include <hip/hip_bf16.h>

#define H 16
#define L 4096
#define D 64
#define R 128
#define C2 64
#define NC2 64
#define HN2 (H * NC2)      // 1024 chunks
#define EPS 1e-10f
#define XS_SCALE 0.125f                    // sqrt(0.125)/64^0.25 == 1/8 exactly
#define PHI_SCALE 0.08838834764831845f     // 1/sqrt(128)

typedef __attribute__((ext_vector_type(8))) short bf8;     // 8 bf16
typedef __attribute__((ext_vector_type(4))) short bf4;     // 4 bf16
typedef __attribute__((ext_vector_type(16))) float facc16; // 32x32 MFMA acc

static __device__ __forceinline__ unsigned short f2b(float f) {
    union { __hip_bfloat16 h; unsigned short u; } c;
    c.h = __float2bfloat16(f);                 // hw v_cvt (RNE), 1 op
    return c.u;
}
static __device__ __forceinline__ float b2f(unsigned short s) {
    return __uint_as_float(((unsigned)s) << 16);
}

// ============== kW: W -> WF (bf16, MFMA-B fragment order) ===================
// WF slot ((tile*4+s)*64 + hi*32 + lo)*8 + e  =  W[d=16s+8hi+e][r=32*tile+lo]
__global__ __launch_bounds__(256) void kW(const float* __restrict__ W,
                                          unsigned short* __restrict__ WF) {
    __shared__ float wl[8192];
    for (int i = threadIdx.x; i < 8192; i += 256) wl[i] = W[i];
    __syncthreads();
    for (int i = threadIdx.x; i < 1024; i += 256) {
        int tile = i >> 8, s = (i >> 6) & 3, hi = (i >> 5) & 1, lo = i & 31;
        int r = tile * 32 + lo;
        #pragma unroll
        for (int e = 0; e < 8; ++e)
            WF[i * 8 + e] = f2b(wl[(16 * s + 8 * hi + e) * 128 + r]);
    }
}

// ============== k1: phi_q, phi_k, vT, skv, zk — 32KB LDS, 5 blocks/CU =======
__global__ __launch_bounds__(256, 4) void k1(
    const float* __restrict__ q, const float* __restrict__ k,
    const float* __restrict__ v, const unsigned short* __restrict__ WF,
    unsigned short* __restrict__ pqF, unsigned short* __restrict__ pkF,
    unsigned short* __restrict__ vTF, unsigned short* __restrict__ skvTp,
    float* __restrict__ zk)
{
    __shared__ __align__(16) unsigned short A_[8192];  // pkT[r][c] swz8 (16KB)
    __shared__ __align__(16) unsigned short C_[8192];  // pq/pk swz16 -> vT swz8 (16KB)
    const int tid = threadIdx.x, hn = blockIdx.x;
    const int lane = tid & 63, wave = tid >> 6, lo = lane & 31, hi = lane >> 5;
    const int rg = wave & 1, ch = wave >> 1;
    const size_t cbase = (size_t)hn * C2 * D;

    // ---- phase 0: q A-frags direct from global + ssq ; phi_q -> C_ ----
    bf8 af[4];
    float sqrow[16];
    {
        float ssq = 0.f;
        #pragma unroll
        for (int s = 0; s < 4; ++s) {
            const float* qp = q + cbase + (rg * 32 + lo) * 64 + 16 * s + 8 * hi;
            float4 f0 = *(const float4*)qp;
            float4 f1 = *(const float4*)(qp + 4);
            float x0 = f0.x * XS_SCALE, x1 = f0.y * XS_SCALE, x2 = f0.z * XS_SCALE, x3 = f0.w * XS_SCALE;
            float x4 = f1.x * XS_SCALE, x5 = f1.y * XS_SCALE, x6 = f1.z * XS_SCALE, x7 = f1.w * XS_SCALE;
            ssq += x0*x0 + x1*x1 + x2*x2 + x3*x3 + x4*x4 + x5*x5 + x6*x6 + x7*x7;
            bf8 a;
            a[0]=(short)f2b(x0); a[1]=(short)f2b(x1); a[2]=(short)f2b(x2); a[3]=(short)f2b(x3);
            a[4]=(short)f2b(x4); a[5]=(short)f2b(x5); a[6]=(short)f2b(x6); a[7]=(short)f2b(x7);
            af[s] = a;
        }
        ssq += __shfl_xor(ssq, 32); ssq *= 0.5f;
        #pragma unroll
        for (int r2 = 0; r2 < 16; ++r2)
            sqrow[r2] = __shfl(ssq, (r2 & 3) + 8 * (r2 >> 2) + 4 * hi);
    }
    {   // phi_q MFMA (B-frags from WF global) -> C_ pq[c][r] swz16
        facc16 acc[2];
        #pragma unroll
        for (int t = 0; t < 2; ++t)
            #pragma unroll
            for (int e = 0; e < 16; ++e) acc[t][e] = 0.f;
        #pragma unroll
        for (int s = 0; s < 4; ++s)
            #pragma unroll
            for (int t = 0; t < 2; ++t) {
                const bf8 b = *(const bf8*)(WF + (((2 * ch + t) * 4 + s) * 64 + hi * 32 + lo) * 8);
                acc[t] = __builtin_amdgcn_mfma_f32_32x32x16_bf16(af[s], b, acc[t], 0, 0, 0);
            }
        #pragma unroll
        for (int t = 0; t < 2; ++t)
            #pragma unroll
            for (int reg = 0; reg < 16; ++reg) {
                int row = rg * 32 + (reg & 3) + 8 * (reg >> 2) + 4 * hi;
                int col = (2 * ch + t) * 32 + lo;
                C_[(unsigned)((row * 128 + col) ^ ((row & 15) << 3))] =
                    f2b(__expf(acc[t][reg] - sqrow[reg]) * PHI_SCALE);
            }
    }
    __syncthreads();                                   // S1

    // ---- phase A: pq frag-dump; k A-frags; phi_k MFMA ----
    {
        int g2 = wave & 1, sh = wave >> 1;
        #pragma unroll
        for (int s2 = 0; s2 < 4; ++s2) {
            int s = sh * 4 + s2;
            bf8 t8 = *(const bf8*)&C_[(unsigned)(((g2 * 32 + lo) * 128 + 16 * s + 8 * hi) ^ ((lo & 15) << 3))];
            *(bf8*)(pqF + (size_t)hn * 8192 + (size_t)(((g2 * 8 + s) * 64 + hi * 32 + lo) * 8)) = t8;
        }
    }
    float sqk[16];
    {
        float ssq = 0.f;
        #pragma unroll
        for (int s = 0; s < 4; ++s) {
            const float* kp = k + cbase + (rg * 32 + lo) * 64 + 16 * s + 8 * hi;
            float4 f0 = *(const float4*)kp;
            float4 f1 = *(const float4*)(kp + 4);
            float x0 = f0.x * XS_SCALE, x1 = f0.y * XS_SCALE, x2 = f0.z * XS_SCALE, x3 = f0.w * XS_SCALE;
            float x4 = f1.x * XS_SCALE, x5 = f1.y * XS_SCALE, x6 = f1.z * XS_SCALE, x7 = f1.w * XS_SCALE;
            ssq += x0*x0 + x1*x1 + x2*x2 + x3*x3 + x4*x4 + x5*x5 + x6*x6 + x7*x7;
            bf8 a;
            a[0]=(short)f2b(x0); a[1]=(short)f2b(x1); a[2]=(short)f2b(x2); a[3]=(short)f2b(x3);
            a[4]=(short)f2b(x4); a[5]=(short)f2b(x5); a[6]=(short)f2b(x6); a[7]=(short)f2b(x7);
            af[s] = a;
        }
        ssq += __shfl_xor(ssq, 32); ssq *= 0.5f;
        #pragma unroll
        for (int r2 = 0; r2 < 16; ++r2)
            sqk[r2] = __shfl(ssq, (r2 & 3) + 8 * (r2 >> 2) + 4 * hi);
    }
    facc16 acck[2];
    #pragma unroll
    for (int t = 0; t < 2; ++t)
        #pragma unroll
        for (int e = 0; e < 16; ++e) acck[t][e] = 0.f;
    #pragma unroll
    for (int s = 0; s < 4; ++s)
        #pragma unroll
        for (int t = 0; t < 2; ++t) {
            const bf8 b = *(const bf8*)(WF + (((2 * ch + t) * 4 + s) * 64 + hi * 32 + lo) * 8);
            acck[t] = __builtin_amdgcn_mfma_f32_32x32x16_bf16(af[s], b, acck[t], 0, 0, 0);
        }
    __syncthreads();                                   // S2 (pq-dump reads done)

    // ---- phase B: pk -> C_ swz16 + pkT -> A_ swz8 ----
    #pragma unroll
    for (int t = 0; t < 2; ++t) {
        int colr = (2 * ch + t) * 32 + lo;
        #pragma unroll
        for (int g = 0; g < 4; ++g) {
            int c0 = rg * 32 + 8 * g + 4 * hi;
            bf4 pk4;
            #pragma unroll
            for (int e = 0; e < 4; ++e) {
                unsigned short bb = f2b(__expf(acck[t][4 * g + e] - sqk[4 * g + e]) * PHI_SCALE);
                pk4[e] = (short)bb;
                C_[(unsigned)(((c0 + e) * 128 + colr) ^ (((c0 + e) & 15) << 3))] = bb;
            }
            *(bf4*)&A_[(unsigned)((colr * 64 + c0) ^ ((colr & 7) << 3))] = pk4;
        }
    }
    __syncthreads();                                   // S3

    // ---- phase C: pk frag-dump; zk (MFMA); vT identity-MFMA (1 tile/wave,
    //               B-frags straight from global fp32 v) ----
    {
        int g2 = wave & 1, sh = wave >> 1;
        #pragma unroll
        for (int s2 = 0; s2 < 4; ++s2) {
            int s = sh * 4 + s2;
            bf8 t8 = *(const bf8*)&C_[(unsigned)(((g2 * 32 + lo) * 128 + 16 * s + 8 * hi) ^ ((lo & 15) << 3))];
            *(bf8*)(pkF + (size_t)hn * 8192 + (size_t)(((g2 * 8 + s) * 64 + hi * 32 + lo) * 8)) = t8;
        }
    }
    {   // zk[r] = rowsum(pkT) via MFMA ones-column; wave handles rows wave*32..+31
        bf8 onesk;
        #pragma unroll
        for (int e = 0; e < 8; ++e) onesk[e] = (lo == 0) ? (short)0x3F80 : (short)0;
        facc16 az;
        #pragma unroll
        for (int e = 0; e < 16; ++e) az[e] = 0.f;
        #pragma unroll
        for (int s = 0; s < 4; ++s) {
            const bf8 a = *(const bf8*)&A_[(unsigned)(((wave * 32 + lo) * 64 + 16 * s + 8 * hi) ^ ((lo & 7) << 3))];
            az = __builtin_amdgcn_mfma_f32_32x32x16_bf16(a, onesk, az, 0, 0, 0);
        }
        if (lo == 0) {
            #pragma unroll
            for (int reg = 0; reg < 16; ++reg)
                zk[(size_t)hn * 128 + wave * 32 + (reg & 3) + 8 * (reg >> 2) + 4 * hi] = az[reg];
        }
    }
    facc16 tv;                                         // vT tile: d-tile=ch, c-tile=rg
    {
        bf8 aid[2];
        #pragma unroll
        for (int s2 = 0; s2 < 2; ++s2)
            #pragma unroll
            for (int e = 0; e < 8; ++e)
                aid[s2][e] = (e == lo - 16 * s2 - 8 * hi) ? (short)0x3F80 : (short)0;
        #pragma unroll
        for (int e = 0; e < 16; ++e) tv[e] = 0.f;
        #pragma unroll
        for (int s2 = 0; s2 < 2; ++s2) {
            const float* vp = v + cbase + (size_t)(32 * rg + lo) * 64 + 16 * (2 * ch + s2) + 8 * hi;
            float4 f0 = *(const float4*)vp;
            float4 f1 = *(const float4*)(vp + 4);
            bf8 b;
            b[0]=(short)f2b(f0.x); b[1]=(short)f2b(f0.y); b[2]=(short)f2b(f0.z); b[3]=(short)f2b(f0.w);
            b[4]=(short)f2b(f1.x); b[5]=(short)f2b(f1.y); b[6]=(short)f2b(f1.z); b[7]=(short)f2b(f1.w);
            tv = __builtin_amdgcn_mfma_f32_32x32x16_bf16(aid[s2], b, tv, 0, 0, 0);
        }
    }
    __syncthreads();                                   // S4 (pk-dump reads done)

    // ---- phase D: vT tile -> C_ [d][c] swz8 ----
    #pragma unroll
    for (int reg = 0; reg < 16; ++reg) {
        int d = 32 * ch + (reg & 3) + 8 * (reg >> 2) + 4 * hi;
        int c = 32 * rg + lo;
        C_[(unsigned)((d * 64 + c) ^ ((d & 7) << 3))] = f2b(tv[reg]);
    }
    __syncthreads();                                   // S5

    // ---- phase E: vT frag-dump; skv MFMA; skvTp dump ----
    {
        int g2 = wave & 1, sh = wave >> 1;
        #pragma unroll
        for (int s2 = 0; s2 < 2; ++s2) {
            int s = sh * 2 + s2;
            bf8 t8 = *(const bf8*)&C_[(unsigned)(((g2 * 32 + lo) * 64 + 16 * s + 8 * hi) ^ ((lo & 7) << 3))];
            *(bf8*)(vTF + (size_t)hn * 4096 + (size_t)(((g2 * 4 + s) * 64 + hi * 32 + lo) * 8)) = t8;
        }
    }
    {
        facc16 acs[2];
        #pragma unroll
        for (int t = 0; t < 2; ++t)
            #pragma unroll
            for (int e = 0; e < 16; ++e) acs[t][e] = 0.f;
        #pragma unroll
        for (int s = 0; s < 4; ++s) {
            const bf8 a = *(const bf8*)&C_[(unsigned)(((rg * 32 + lo) * 64 + 16 * s + 8 * hi) ^ ((lo & 7) << 3))];
            #pragma unroll
            for (int t = 0; t < 2; ++t) {
                const bf8 b = *(const bf8*)&A_[(unsigned)((((2 * ch + t) * 32 + lo) * 64 + 16 * s + 8 * hi) ^ ((lo & 7) << 3))];
                acs[t] = __builtin_amdgcn_mfma_f32_32x32x16_bf16(a, b, acs[t], 0, 0, 0);
            }
        }
        unsigned short* sg = skvTp + (size_t)hn * 8192;
        #pragma unroll
        for (int t = 0; t < 2; ++t)
            #pragma unroll
            for (int reg = 0; reg < 16; ++reg) {
                int d = rg * 32 + (reg & 3) + 8 * (reg >> 2) + 4 * hi;
                int r = (2 * ch + t) * 32 + lo;
                sg[d * 128 + r] = f2b(acs[t][reg]);
            }
    }
}

// ============== k2: exclusive prefix over chunks (R9 form, coalesced) =======
__global__ __launch_bounds__(256) void k2(unsigned short* __restrict__ skvTp,
                                          const float* __restrict__ zk,
                                          unsigned short* __restrict__ zkp)
{
    const int bid = blockIdx.x, tid = threadIdx.x;
    if (bid < 512) {
        int g = bid * 256 + tid;                       // H*D*R = 131072 cols
        int h = g >> 13, dr = g & 8191;
        unsigned short* p = skvTp + (size_t)h * NC2 * 8192 + dr;
        unsigned short vals[NC2];
        #pragma unroll
        for (int n = 0; n < NC2; ++n) vals[n] = p[(size_t)n * 8192];
        float run = 0.f;
        #pragma unroll
        for (int n = 0; n < NC2; ++n) {
            float t = b2f(vals[n]);
            p[(size_t)n * 8192] = f2b(run);
            run += t;
        }
    } else {
        int g2 = (bid - 512) * 256 + tid;              // H*R = 2048 cols
        int h = g2 >> 7, r = g2 & 127;
        const float* pz = zk + (size_t)h * NC2 * 128 + r;
        unsigned short* oz = zkp + (size_t)h * NC2 * 128 + r;
        float vals[NC2];
        #pragma unroll
        for (int n = 0; n < NC2; ++n) vals[n] = pz[n * 128];
        float run = 0.f;
        #pragma unroll
        for (int n = 0; n < NC2; ++n) {
            oz[n * 128] = f2b(run);
            run += vals[n];
        }
    }
}

// ============== k3: GEMM1 + mask + num/den GEMM + divide (1 barrier) ========
__global__ __launch_bounds__(256) void k3(
    const unsigned short* __restrict__ pqF, const unsigned short* __restrict__ pkF,
    const unsigned short* __restrict__ vTF, const unsigned short* __restrict__ skvTp,
    const unsigned short* __restrict__ zkp, float* __restrict__ out)
{
    __shared__ __align__(16) unsigned short P_[8192];  // svl [d][r] swz16 (16KB)
    __shared__ __align__(16) unsigned short S_[4096];  // A_att [l][s] swz8 (8KB)
    const int tid = threadIdx.x, hn = blockIdx.x;
    const int lane = tid & 63, wave = tid >> 6, lo = lane & 31, hi = lane >> 5;
    const int rg = wave & 1, ch = wave >> 1;

    for (int i = tid; i < 1024; i += 256) {            // stage svl early
        bf8 t8 = *(const bf8*)(skvTp + (size_t)hn * 8192 + (size_t)i * 8);
        int d = i >> 4, r0 = (i & 15) * 8;
        *(bf8*)&P_[(unsigned)((d * 128 + r0) ^ ((d & 15) << 3))] = t8;
    }
    bf8 qf[8];
    #pragma unroll
    for (int s = 0; s < 8; ++s)
        qf[s] = *(const bf8*)(pqF + (size_t)hn * 8192 + (size_t)(((rg * 8 + s) * 64 + hi * 32 + lo) * 8));
    bf8 onesf, zf[8];
    #pragma unroll
    for (int e = 0; e < 8; ++e) onesf[e] = (lo == 0) ? (short)0x3F80 : (short)0;
    #pragma unroll
    for (int s = 0; s < 8; ++s)
        #pragma unroll
        for (int e = 0; e < 8; ++e) zf[s][e] = 0;
    if (lo == 0) {
        #pragma unroll
        for (int s = 0; s < 8; ++s)
            zf[s] = *(const bf8*)(zkp + (size_t)hn * 128 + 16 * s + 8 * hi);
    }

    facc16 ac1;                                        // GEMM1: A = pq.pk^T
    #pragma unroll
    for (int e = 0; e < 16; ++e) ac1[e] = 0.f;
    #pragma unroll
    for (int s = 0; s < 8; ++s) {
        const bf8 b = *(const bf8*)(pkF + (size_t)hn * 8192 + (size_t)(((ch * 8 + s) * 64 + hi * 32 + lo) * 8));
        ac1 = __builtin_amdgcn_mfma_f32_32x32x16_bf16(qf[s], b, ac1, 0, 0, 0);
    }
    #pragma unroll
    for (int reg = 0; reg < 16; ++reg) {               // masked A -> S_
        int row = rg * 32 + (reg & 3) + 8 * (reg >> 2) + 4 * hi;
        int sc = ch * 32 + lo;
        S_[(unsigned)((row * 64 + sc) ^ ((row & 7) << 3))] = f2b(sc < row ? ac1[reg] : 0.f);
    }
    __syncthreads();                                   // S1 (A_att + svl visible)

    facc16 an, ad;
    #pragma unroll
    for (int e = 0; e < 16; ++e) { an[e] = 0.f; ad[e] = 0.f; }
    #pragma unroll
    for (int s = 0; s < 4; ++s) {                      // pass A: k = c
        const bf8 a = *(const bf8*)&S_[(unsigned)(((rg * 32 + lo) * 64 + 16 * s + 8 * hi) ^ ((lo & 7) << 3))];
        const bf8 b = *(const bf8*)(vTF + (size_t)hn * 4096 + (size_t)(((ch * 4 + s) * 64 + hi * 32 + lo) * 8));
        an = __builtin_amdgcn_mfma_f32_32x32x16_bf16(a, b, an, 0, 0, 0);
        ad = __builtin_amdgcn_mfma_f32_32x32x16_bf16(a, onesf, ad, 0, 0, 0);
    }
    #pragma unroll
    for (int s = 0; s < 8; ++s) {                      // pass B: k = r
        const bf8 b = *(const bf8*)&P_[(unsigned)(((ch * 32 + lo) * 128 + 16 * s + 8 * hi) ^ ((lo & 15) << 3))];
        an = __builtin_amdgcn_mfma_f32_32x32x16_bf16(qf[s], b, an, 0, 0, 0);
        ad = __builtin_amdgcn_mfma_f32_32x32x16_bf16(qf[s], zf[s], ad, 0, 0, 0);
    }
    float* og = out + (size_t)hn * C2 * D;
    #pragma unroll
    for (int reg = 0; reg < 16; ++reg) {
        int row = rg * 32 + (reg & 3) + 8 * (reg >> 2) + 4 * hi;
        float dv = __shfl(ad[reg], lane & 32);
        og[row * 64 + ch * 32 + lo] = an[reg] / (dv + EPS);
    }
}

// ---------------------------------------------------------------------------
extern "C" void kernel_launch(void* const* d_in, const int* in_sizes, int n_in,
                              void* d_out, int out_size, void* d_ws, size_t ws_size,
                              hipStream_t stream) {
    // setup_inputs order: {T, k, q, v, W}
    const float* k = (const float*)d_in[1];
    const float* q = (const float*)d_in[2];
    const float* v = (const float*)d_in[3];
    const float* W = (const float*)d_in[4];
    float* out = (float*)d_out;

    // ws (u16 units): pqF 16MB | pkF 16MB | vTF 8MB | skvTp 16MB | WF | zkp | zk
    unsigned short* pqF   = (unsigned short*)d_ws;
    unsigned short* pkF   = pqF + (size_t)HN2 * 8192;
    unsigned short* vTF   = pkF + (size_t)HN2 * 8192;
    unsigned short* skvTp = vTF + (size_t)HN2 * 4096;
    unsigned short* WF    = skvTp + (size_t)HN2 * 8192;
    unsigned short* zkp   = WF + 8192;
    float* zk             = (float*)(zkp + (size_t)HN2 * 128);

    kW<<<1, 256, 0, stream>>>(W, WF);
    k1<<<HN2, 256, 0, stream>>>(q, k, v, WF, pqF, pkF, vTF, skvTp, zk);
    k2<<<520, 256, 0, stream>>>(skvTp, zk, zkp);
    k3<<<HN2, 256, 0, stream>>>(pqF, pkF, vTF, skvTp, zkp, out);
}